// Round 3
// baseline (556.301 us; speedup 1.0000x reference)
//
#include <hip/hip_runtime.h>
#include <hip/hip_bf16.h>

// Problem constants (match reference)
#define NB 128          // graphs
#define NN 512          // nodes per graph
#define NF 128          // feature dim
#define BN (NB*NN)      // 65536 total nodes
#define NE (BN*16)      // 1048576 edges
#define WPR 16          // bitmap words per row (512 bits / 32)
#define ELLW 64         // ELL width (max padded degree; Poisson(16) max << 64)

// ---------------------------------------------------------------------------
// Adjacency build: bitmap with set-semantics dedup + out-degree count
// ---------------------------------------------------------------------------
__global__ __launch_bounds__(256) void build_adj_kernel(
    const int* __restrict__ src, const int* __restrict__ dst,
    unsigned* __restrict__ bitmap, int* __restrict__ deg)
{
    int e = blockIdx.x * 256 + threadIdx.x;
    int s = src[e];
    int d = dst[e];
    int col = d & (NN - 1);                 // column within graph
    unsigned word = (unsigned)s * WPR + (col >> 5);
    unsigned mask = 1u << (col & 31);
    unsigned old = atomicOr(&bitmap[word], mask);
    if (!(old & mask)) atomicAdd(&deg[s], 1);
}

__global__ __launch_bounds__(256) void dinv_kernel(
    const int* __restrict__ deg, float* __restrict__ dinv)
{
    int i = blockIdx.x * 256 + threadIdx.x;
    int d = deg[i];
    dinv[i] = (d > 0) ? rsqrtf((float)d) : 0.0f;
}

// ---------------------------------------------------------------------------
// ELL build: per row, enumerate set bits -> local neighbor indices (0..511),
// pad to multiple of 4 with sentinel 512 (points at a zeroed LDS row).
// ---------------------------------------------------------------------------
__global__ __launch_bounds__(256) void ell_build_kernel(
    const unsigned* __restrict__ bitmap, int* __restrict__ ell,
    int* __restrict__ ellcnt)
{
    int row = blockIdx.x * 256 + threadIdx.x;
    int* er = ell + (size_t)row * ELLW;
    int c = 0;
    #pragma unroll
    for (int w = 0; w < WPR; ++w) {
        unsigned bits = bitmap[(size_t)row * WPR + w];
        while (bits) {
            int j = __ffs(bits) - 1;
            bits &= bits - 1;
            er[c++] = w * 32 + j;
        }
    }
    while (c & 3) er[c++] = NN;     // sentinel -> zero row
    ellcnt[row] = c;
}

// ---------------------------------------------------------------------------
// Fused 3-hop poly conv, one block per (graph, feature-half).
// LDS holds w = dinv .* z for all 512 rows x 64 features (+1 zero row).
// Wave = 64 lanes over features; wave owns 32 rows. Gather w[j*64+lane] is
// conflict-free (2-way bank aliasing). acc = x + z1 + z2 + z3 in registers.
// ---------------------------------------------------------------------------
__global__ __launch_bounds__(1024, 1) void poly_fused_kernel(
    const float* __restrict__ xin,      // [BN, NF]
    float* __restrict__ accout,         // [BN, NF]
    const int* __restrict__ ell,        // [BN, ELLW] local indices
    const int* __restrict__ ellcnt,     // [BN] padded counts (mult of 4)
    const float* __restrict__ dinv)
{
    extern __shared__ float lds[];
    float* w   = lds;                   // (NN+1)*64
    float* dsh = lds + (NN + 1) * 64;   // NN

    int b = blockIdx.x;                 // 0..255
    int g = b >> 1;
    int h = b & 1;
    int t = threadIdx.x;
    int lane = t & 63;
    int wid = t >> 6;                   // 0..15
    int row0 = wid * 32;

    if (t < NN) dsh[t] = dinv[(size_t)g * NN + t];
    if (t >= 960) w[NN * 64 + (t - 960)] = 0.0f;   // zero sentinel row

    const float* xg = xin + (size_t)g * NN * NF + h * 64 + lane;

    float acc[32];
    #pragma unroll
    for (int rr = 0; rr < 32; ++rr)
        acc[rr] = xg[(size_t)(row0 + rr) * NF];

    __syncthreads();                    // dsh + sentinel ready

    #pragma unroll
    for (int rr = 0; rr < 32; ++rr)
        w[(row0 + rr) * 64 + lane] = dsh[row0 + rr] * acc[rr];
    __syncthreads();                    // w init ready

    const int* ellg = ell + (size_t)g * NN * ELLW;
    const int* cntg = ellcnt + (size_t)g * NN;
    int wrow = __builtin_amdgcn_readfirstlane(row0);

    for (int hop = 0; hop < 3; ++hop) {
        float stage[32];
        #pragma unroll
        for (int rr = 0; rr < 32; ++rr) {
            int rowu = wrow + rr;
            int cnt = cntg[rowu];               // wave-uniform scalar load
            const int* el = ellg + rowu * ELLW;
            float s = 0.0f;
            for (int p = 0; p < cnt; p += 4) {
                int j0 = el[p + 0];
                int j1 = el[p + 1];
                int j2 = el[p + 2];
                int j3 = el[p + 3];
                s += w[j0 * 64 + lane];
                s += w[j1 * 64 + lane];
                s += w[j2 * 64 + lane];
                s += w[j3 * 64 + lane];
            }
            stage[rr] = s;
        }
        __syncthreads();                // all reads of old w done
        #pragma unroll
        for (int rr = 0; rr < 32; ++rr) {
            float di = dsh[row0 + rr];
            float z = di * stage[rr];   // z_{k+1}[row]
            acc[rr] += z;
            w[(row0 + rr) * 64 + lane] = di * z;   // w = dinv .* z
        }
        __syncthreads();                // new w visible
    }

    float* og = accout + (size_t)g * NN * NF + h * 64 + lane;
    #pragma unroll
    for (int rr = 0; rr < 32; ++rr)
        og[(size_t)(row0 + rr) * NF] = acc[rr];
}

// ---------------------------------------------------------------------------
// GEMM: Y[65536,128] = relu(X @ W[128,128] + b)
// block: 256 threads, 64 rows x 128 cols per block; thread: 4 rows x 8 cols
// ---------------------------------------------------------------------------
__global__ __launch_bounds__(256) void gemm_bias_relu_kernel(
    const float* __restrict__ X, const float* __restrict__ W,
    const float* __restrict__ b, float* __restrict__ Y)
{
    __shared__ float Ws[NF * NF];
    for (int i = threadIdx.x; i < NF * NF / 4; i += 256) {
        ((float4*)Ws)[i] = ((const float4*)W)[i];
    }
    __syncthreads();

    int rg = threadIdx.x >> 4;              // 0..15
    int cg = threadIdx.x & 15;              // 0..15
    int row0 = blockIdx.x * 64 + rg * 4;
    int col0 = cg * 8;

    float acc[4][8];
    #pragma unroll
    for (int r = 0; r < 4; ++r)
        #pragma unroll
        for (int c = 0; c < 8; ++c) acc[r][c] = 0.0f;

    for (int k = 0; k < NF; k += 4) {
        float4 xv[4];
        #pragma unroll
        for (int r = 0; r < 4; ++r)
            xv[r] = *(const float4*)&X[(size_t)(row0 + r) * NF + k];
        #pragma unroll
        for (int kk = 0; kk < 4; ++kk) {
            float wv[8];
            #pragma unroll
            for (int c = 0; c < 8; ++c) wv[c] = Ws[(k + kk) * NF + col0 + c];
            #pragma unroll
            for (int r = 0; r < 4; ++r) {
                float x = (kk == 0) ? xv[r].x : (kk == 1) ? xv[r].y
                        : (kk == 2) ? xv[r].z : xv[r].w;
                #pragma unroll
                for (int c = 0; c < 8; ++c) acc[r][c] += x * wv[c];
            }
        }
    }

    #pragma unroll
    for (int r = 0; r < 4; ++r) {
        float out[8];
        #pragma unroll
        for (int c = 0; c < 8; ++c) {
            float v = acc[r][c] + b[col0 + c];
            out[c] = fmaxf(v, 0.0f);
        }
        float* yp = &Y[(size_t)(row0 + r) * NF + col0];
        *(float4*)&yp[0] = *(float4*)&out[0];
        *(float4*)&yp[4] = *(float4*)&out[4];
    }
}

// ---------------------------------------------------------------------------
// Mean pool over nodes + 2-layer MLP readout. One block (256 thr) per graph.
// ---------------------------------------------------------------------------
__global__ __launch_bounds__(256) void pool_readout_kernel(
    const float* __restrict__ Y,
    const float* __restrict__ Wr1, const float* __restrict__ br1,
    const float* __restrict__ Wr2, const float* __restrict__ br2,
    float* __restrict__ out)
{
    __shared__ float partial[256];
    __shared__ float hsh[NF];
    __shared__ float r1[64];

    int g = blockIdx.x;
    int t = threadIdx.x;
    int f = t & (NF - 1);
    int half = t >> 7;

    const float* base = Y + (size_t)g * NN * NF;
    float s = 0.0f;
    for (int r = half * 256; r < half * 256 + 256; ++r)
        s += base[(size_t)r * NF + f];
    partial[t] = s;
    __syncthreads();

    if (t < NF) hsh[t] = (partial[t] + partial[t + NF]) * (1.0f / (float)NN);
    __syncthreads();

    if (t < 64) {
        float a = br1[t];
        #pragma unroll 8
        for (int k = 0; k < NF; ++k) a += hsh[k] * Wr1[k * 64 + t];
        r1[t] = fmaxf(a, 0.0f);
    }
    __syncthreads();

    if (t < 64) {
        float v = r1[t] * Wr2[t];
        #pragma unroll
        for (int off = 32; off; off >>= 1) v += __shfl_down(v, off);
        if (t == 0) out[g] = v + br2[0];
    }
}

// ---------------------------------------------------------------------------
extern "C" void kernel_launch(void* const* d_in, const int* in_sizes, int n_in,
                              void* d_out, int out_size, void* d_ws, size_t ws_size,
                              hipStream_t stream)
{
    const float* X    = (const float*)d_in[0];
    // d_in[1] = batch (unused; nodes already grouped per graph)
    const int*   ei   = (const int*)d_in[2];
    const float* W1   = (const float*)d_in[3];
    const float* b1   = (const float*)d_in[4];
    const float* W2   = (const float*)d_in[5];
    const float* b2   = (const float*)d_in[6];
    const float* Wr1  = (const float*)d_in[7];
    const float* br1  = (const float*)d_in[8];
    const float* Wr2  = (const float*)d_in[9];
    const float* br2  = (const float*)d_in[10];
    float* out = (float*)d_out;

    const int* src = ei;
    const int* dst = ei + NE;

    // workspace layout
    char* ws = (char*)d_ws;
    unsigned* bitmap = (unsigned*)(ws);                        // 4 MB
    int*      deg    = (int*)(ws + (size_t)4096 * 1024);       // 256 KB
    float*    dinv   = (float*)(ws + (size_t)4352 * 1024);     // 256 KB
    int*      ellcnt = (int*)(ws + (size_t)4608 * 1024);       // 256 KB
    int*      ell    = (int*)(ws + (size_t)8192 * 1024);       // 16 MB
    float*    buf0   = (float*)(ws + (size_t)24576 * 1024);    // 32 MB
    float*    buf1   = (float*)(ws + (size_t)57344 * 1024);    // 32 MB

    // zero bitmap + deg (4 MB + 256 KB contiguous)
    hipMemsetAsync(d_ws, 0, (size_t)4352 * 1024, stream);

    build_adj_kernel<<<NE / 256, 256, 0, stream>>>(src, dst, bitmap, deg);
    dinv_kernel<<<BN / 256, 256, 0, stream>>>(deg, dinv);
    ell_build_kernel<<<BN / 256, 256, 0, stream>>>(bitmap, ell, ellcnt);

    const size_t LDSSZ = ((NN + 1) * 64 + NN) * sizeof(float);  // 133,376 B

    // ---- Layer 1
    poly_fused_kernel<<<NB * 2, 1024, LDSSZ, stream>>>(X, buf0, ell, ellcnt, dinv);
    gemm_bias_relu_kernel<<<BN / 64, 256, 0, stream>>>(buf0, W1, b1, buf1);

    // ---- Layer 2
    poly_fused_kernel<<<NB * 2, 1024, LDSSZ, stream>>>(buf1, buf0, ell, ellcnt, dinv);
    gemm_bias_relu_kernel<<<BN / 64, 256, 0, stream>>>(buf0, W2, b2, buf1);

    // ---- Pool + readout
    pool_readout_kernel<<<NB, 256, 0, stream>>>(buf1, Wr1, br1, Wr2, br2, out);
}

// Round 4
// 497.820 us; speedup vs baseline: 1.1175x; 1.1175x over previous
//
#include <hip/hip_runtime.h>
#include <hip/hip_bf16.h>

// Problem constants (match reference)
#define NB 128          // graphs
#define NN 512          // nodes per graph
#define NF 128          // feature dim
#define BN (NB*NN)      // 65536 total nodes
#define NE (BN*16)      // 1048576 edges
#define WPR 16          // bitmap words per row (512 bits / 32)
#define ELLW 64         // ELL width (max padded degree; Poisson(16) max << 64)

// ---------------------------------------------------------------------------
// Adjacency build: bitmap with set-semantics dedup + out-degree count
// ---------------------------------------------------------------------------
__global__ __launch_bounds__(256) void build_adj_kernel(
    const int* __restrict__ src, const int* __restrict__ dst,
    unsigned* __restrict__ bitmap, int* __restrict__ deg)
{
    int e = blockIdx.x * 256 + threadIdx.x;
    int s = src[e];
    int d = dst[e];
    int col = d & (NN - 1);                 // column within graph
    unsigned word = (unsigned)s * WPR + (col >> 5);
    unsigned mask = 1u << (col & 31);
    unsigned old = atomicOr(&bitmap[word], mask);
    if (!(old & mask)) atomicAdd(&deg[s], 1);
}

__global__ __launch_bounds__(256) void dinv_kernel(
    const int* __restrict__ deg, float* __restrict__ dinv)
{
    int i = blockIdx.x * 256 + threadIdx.x;
    int d = deg[i];
    dinv[i] = (d > 0) ? rsqrtf((float)d) : 0.0f;
}

// ---------------------------------------------------------------------------
// ELL build, column-major ushort: ell[g][p][n] at g*NN*ELLW + p*NN + n.
// Writes are coalesced across threads (consecutive n). Pad cnt to mult of 4
// with sentinel NN (zero row in LDS).
// ---------------------------------------------------------------------------
__global__ __launch_bounds__(256) void ell_build_kernel(
    const unsigned* __restrict__ bitmap, unsigned short* __restrict__ ell,
    int* __restrict__ ellcnt)
{
    int row = blockIdx.x * 256 + threadIdx.x;
    int g = row >> 9;
    int n = row & (NN - 1);
    unsigned short* er = ell + (size_t)g * NN * ELLW + n;
    int c = 0;
    #pragma unroll
    for (int w = 0; w < WPR; ++w) {
        unsigned bits = bitmap[(size_t)row * WPR + w];
        while (bits) {
            int j = __ffs(bits) - 1;
            bits &= bits - 1;
            er[(size_t)c * NN] = (unsigned short)(w * 32 + j);
            ++c;
        }
    }
    while (c & 3) { er[(size_t)c * NN] = (unsigned short)NN; ++c; }
    ellcnt[row] = c;
}

// ---------------------------------------------------------------------------
// Fused 3-hop poly conv, one block per (graph, feature-half).
// LDS: w = dinv.*z for 512 rows x 64 features (+ zero sentinel row 512).
// Wave layout: lane = (slot=lane>>4, fq=lane&15). Wave owns 32 rows; in each
// of 8 quads, slot s owns row 4q+s entirely, lane holds float4 of features
// 4fq..4fq+3. Gather is ds_read_b128 (4 rows x 256 B per instr, conflict-free
// per the stride-1-equivalent bank pattern). No cross-lane reduction needed.
// ---------------------------------------------------------------------------
__global__ __launch_bounds__(1024, 1) void poly_fused_kernel(
    const float* __restrict__ xin,            // [BN, NF]
    float* __restrict__ accout,               // [BN, NF]
    const unsigned short* __restrict__ ell,   // [NB][ELLW][NN] column-major
    const int* __restrict__ ellcnt,           // [BN] padded counts (mult 4)
    const float* __restrict__ dinv)
{
    extern __shared__ float lds[];
    float* w   = lds;                    // (NN+1)*64
    float* dsh = lds + (NN + 1) * 64;    // NN

    int b = blockIdx.x;
    int g = b >> 1;
    int h = b & 1;
    int t = threadIdx.x;
    int lane = t & 63;
    int wid  = t >> 6;                   // 0..15
    int slot = lane >> 4;                // 0..3
    int fq   = lane & 15;                // 0..15

    if (t < NN) dsh[t] = dinv[(size_t)g * NN + t];
    if (t < 64) w[NN * 64 + t] = 0.0f;   // zero sentinel row

    int rq0 = wid * 32;                  // first row of this wave
    int rown = rq0 + slot;               // own row for quad q is rown + 4q

    const float* xg = xin + (size_t)g * NN * NF + h * 64 + fq * 4;

    float4 acc[8];
    #pragma unroll
    for (int q = 0; q < 8; ++q)
        acc[q] = *(const float4*)&xg[(size_t)(rown + 4 * q) * NF];

    __syncthreads();                     // dsh + sentinel ready

    #pragma unroll
    for (int q = 0; q < 8; ++q) {
        int row = rown + 4 * q;
        float di = dsh[row];
        float4 v;
        v.x = di * acc[q].x; v.y = di * acc[q].y;
        v.z = di * acc[q].z; v.w = di * acc[q].w;
        *(float4*)&w[row * 64 + fq * 4] = v;
    }
    __syncthreads();                     // w init ready

    const unsigned short* ellg = ell + (size_t)g * NN * ELLW;
    const int* cntg = ellcnt + (size_t)g * NN;

    for (int hop = 0; hop < 3; ++hop) {
        float4 stage[8];
        #pragma unroll
        for (int q = 0; q < 8; ++q) {
            int rqu = __builtin_amdgcn_readfirstlane(rq0 + 4 * q);
            int c0 = cntg[rqu + 0];      // wave-uniform scalar loads
            int c1 = cntg[rqu + 1];
            int c2 = cntg[rqu + 2];
            int c3 = cntg[rqu + 3];
            int cmax = max(max(c0, c1), max(c2, c3));
            int cown = (slot == 0) ? c0 : (slot == 1) ? c1
                     : (slot == 2) ? c2 : c3;
            const unsigned short* el = ellg + (rqu + slot);
            float4 s = {0.0f, 0.0f, 0.0f, 0.0f};
            for (int p = 0; p < cmax; ++p) {
                int jr = (int)el[(size_t)p * NN];
                int j = (p < cown) ? jr : NN;     // sentinel -> zero row
                float4 v = *(const float4*)&w[j * 64 + fq * 4];
                s.x += v.x; s.y += v.y; s.z += v.z; s.w += v.w;
            }
            stage[q] = s;
        }
        __syncthreads();                 // all reads of old w done
        #pragma unroll
        for (int q = 0; q < 8; ++q) {
            int row = rown + 4 * q;
            float di = dsh[row];
            float4 z;
            z.x = di * stage[q].x; z.y = di * stage[q].y;
            z.z = di * stage[q].z; z.w = di * stage[q].w;
            acc[q].x += z.x; acc[q].y += z.y;
            acc[q].z += z.z; acc[q].w += z.w;
            float4 wv;
            wv.x = di * z.x; wv.y = di * z.y;
            wv.z = di * z.z; wv.w = di * z.w;
            *(float4*)&w[row * 64 + fq * 4] = wv;
        }
        __syncthreads();                 // new w visible
    }

    float* og = accout + (size_t)g * NN * NF + h * 64 + fq * 4;
    #pragma unroll
    for (int q = 0; q < 8; ++q)
        *(float4*)&og[(size_t)(rown + 4 * q) * NF] = acc[q];
}

// ---------------------------------------------------------------------------
// GEMM: Y[65536,128] = relu(X @ W[128,128] + b)
// block: 256 threads, 64 rows x 128 cols per block; thread: 4 rows x 8 cols
// ---------------------------------------------------------------------------
__global__ __launch_bounds__(256) void gemm_bias_relu_kernel(
    const float* __restrict__ X, const float* __restrict__ W,
    const float* __restrict__ b, float* __restrict__ Y)
{
    __shared__ float Ws[NF * NF];
    for (int i = threadIdx.x; i < NF * NF / 4; i += 256) {
        ((float4*)Ws)[i] = ((const float4*)W)[i];
    }
    __syncthreads();

    int rg = threadIdx.x >> 4;              // 0..15
    int cg = threadIdx.x & 15;              // 0..15
    int row0 = blockIdx.x * 64 + rg * 4;
    int col0 = cg * 8;

    float acc[4][8];
    #pragma unroll
    for (int r = 0; r < 4; ++r)
        #pragma unroll
        for (int c = 0; c < 8; ++c) acc[r][c] = 0.0f;

    for (int k = 0; k < NF; k += 4) {
        float4 xv[4];
        #pragma unroll
        for (int r = 0; r < 4; ++r)
            xv[r] = *(const float4*)&X[(size_t)(row0 + r) * NF + k];
        #pragma unroll
        for (int kk = 0; kk < 4; ++kk) {
            float wv[8];
            #pragma unroll
            for (int c = 0; c < 8; ++c) wv[c] = Ws[(k + kk) * NF + col0 + c];
            #pragma unroll
            for (int r = 0; r < 4; ++r) {
                float x = (kk == 0) ? xv[r].x : (kk == 1) ? xv[r].y
                        : (kk == 2) ? xv[r].z : xv[r].w;
                #pragma unroll
                for (int c = 0; c < 8; ++c) acc[r][c] += x * wv[c];
            }
        }
    }

    #pragma unroll
    for (int r = 0; r < 4; ++r) {
        float out[8];
        #pragma unroll
        for (int c = 0; c < 8; ++c) {
            float v = acc[r][c] + b[col0 + c];
            out[c] = fmaxf(v, 0.0f);
        }
        float* yp = &Y[(size_t)(row0 + r) * NF + col0];
        *(float4*)&yp[0] = *(float4*)&out[0];
        *(float4*)&yp[4] = *(float4*)&out[4];
    }
}

// ---------------------------------------------------------------------------
// Mean pool over nodes + 2-layer MLP readout. One block (256 thr) per graph.
// ---------------------------------------------------------------------------
__global__ __launch_bounds__(256) void pool_readout_kernel(
    const float* __restrict__ Y,
    const float* __restrict__ Wr1, const float* __restrict__ br1,
    const float* __restrict__ Wr2, const float* __restrict__ br2,
    float* __restrict__ out)
{
    __shared__ float partial[256];
    __shared__ float hsh[NF];
    __shared__ float r1[64];

    int g = blockIdx.x;
    int t = threadIdx.x;
    int f = t & (NF - 1);
    int half = t >> 7;

    const float* base = Y + (size_t)g * NN * NF;
    float s = 0.0f;
    for (int r = half * 256; r < half * 256 + 256; ++r)
        s += base[(size_t)r * NF + f];
    partial[t] = s;
    __syncthreads();

    if (t < NF) hsh[t] = (partial[t] + partial[t + NF]) * (1.0f / (float)NN);
    __syncthreads();

    if (t < 64) {
        float a = br1[t];
        #pragma unroll 8
        for (int k = 0; k < NF; ++k) a += hsh[k] * Wr1[k * 64 + t];
        r1[t] = fmaxf(a, 0.0f);
    }
    __syncthreads();

    if (t < 64) {
        float v = r1[t] * Wr2[t];
        #pragma unroll
        for (int off = 32; off; off >>= 1) v += __shfl_down(v, off);
        if (t == 0) out[g] = v + br2[0];
    }
}

// ---------------------------------------------------------------------------
extern "C" void kernel_launch(void* const* d_in, const int* in_sizes, int n_in,
                              void* d_out, int out_size, void* d_ws, size_t ws_size,
                              hipStream_t stream)
{
    const float* X    = (const float*)d_in[0];
    // d_in[1] = batch (unused; nodes already grouped per graph)
    const int*   ei   = (const int*)d_in[2];
    const float* W1   = (const float*)d_in[3];
    const float* b1   = (const float*)d_in[4];
    const float* W2   = (const float*)d_in[5];
    const float* b2   = (const float*)d_in[6];
    const float* Wr1  = (const float*)d_in[7];
    const float* br1  = (const float*)d_in[8];
    const float* Wr2  = (const float*)d_in[9];
    const float* br2  = (const float*)d_in[10];
    float* out = (float*)d_out;

    const int* src = ei;
    const int* dst = ei + NE;

    // workspace layout
    char* ws = (char*)d_ws;
    unsigned*       bitmap = (unsigned*)(ws);                        // 4 MB
    int*            deg    = (int*)(ws + (size_t)4096 * 1024);       // 256 KB
    float*          dinv   = (float*)(ws + (size_t)4352 * 1024);     // 256 KB
    int*            ellcnt = (int*)(ws + (size_t)4608 * 1024);       // 256 KB
    unsigned short* ell    = (unsigned short*)(ws + (size_t)8192 * 1024); // 8 MB
    float*          buf0   = (float*)(ws + (size_t)24576 * 1024);    // 32 MB
    float*          buf1   = (float*)(ws + (size_t)57344 * 1024);    // 32 MB

    // zero bitmap + deg (4 MB + 256 KB contiguous)
    hipMemsetAsync(d_ws, 0, (size_t)4352 * 1024, stream);

    build_adj_kernel<<<NE / 256, 256, 0, stream>>>(src, dst, bitmap, deg);
    dinv_kernel<<<BN / 256, 256, 0, stream>>>(deg, dinv);
    ell_build_kernel<<<BN / 256, 256, 0, stream>>>(bitmap, ell, ellcnt);

    const size_t LDSSZ = ((NN + 1) * 64 + NN) * sizeof(float);  // 133,376 B

    // ---- Layer 1
    poly_fused_kernel<<<NB * 2, 1024, LDSSZ, stream>>>(X, buf0, ell, ellcnt, dinv);
    gemm_bias_relu_kernel<<<BN / 64, 256, 0, stream>>>(buf0, W1, b1, buf1);

    // ---- Layer 2
    poly_fused_kernel<<<NB * 2, 1024, LDSSZ, stream>>>(buf1, buf0, ell, ellcnt, dinv);
    gemm_bias_relu_kernel<<<BN / 64, 256, 0, stream>>>(buf0, W2, b2, buf1);

    // ---- Pool + readout
    pool_readout_kernel<<<NB, 256, 0, stream>>>(buf1, Wr1, br1, Wr2, br2, out);
}

// Round 6
// 418.898 us; speedup vs baseline: 1.3280x; 1.1884x over previous
//
#include <hip/hip_runtime.h>
#include <hip/hip_bf16.h>

// Problem constants (match reference)
#define NB 128          // graphs
#define NN 512          // nodes per graph
#define NF 128          // feature dim
#define BN (NB*NN)      // 65536 total nodes
#define NE (BN*16)      // 1048576 edges
#define WPR 16          // bitmap words per row (512 bits / 32)
#define ELLW 64         // ELL width (max padded degree; Poisson(16) max << 64)
#define XS_STRIDE 132   // gemm X LDS stride (floats): breaks 4-row bank alias

// ---------------------------------------------------------------------------
// Adjacency build: bitmap with set-semantics dedup (pure atomicOr)
// ---------------------------------------------------------------------------
__global__ __launch_bounds__(256) void build_adj_kernel(
    const int* __restrict__ src, const int* __restrict__ dst,
    unsigned* __restrict__ bitmap)
{
    int e = blockIdx.x * 256 + threadIdx.x;
    int s = src[e];
    int d = dst[e];
    int col = d & (NN - 1);                 // column within graph
    unsigned word = (unsigned)s * WPR + (col >> 5);
    unsigned mask = 1u << (col & 31);
    atomicOr(&bitmap[word], mask);
}

// ---------------------------------------------------------------------------
// ELL build, ROW-major ushort: ell[row][p]. Fully initializes all ELLW
// entries of every row (sentinel NN beyond the real neighbors) so no ELL
// byte is ever read uninitialized (d_ws is poisoned 0xAA between calls!).
// Also computes dinv (exact degree) and per-quad padded count via LDS max.
// ---------------------------------------------------------------------------
__global__ __launch_bounds__(256) void ell_build_kernel(
    const unsigned* __restrict__ bitmap, unsigned short* __restrict__ ell,
    int* __restrict__ qcnt, float* __restrict__ dinv)
{
    __shared__ int cs[256];
    int row = blockIdx.x * 256 + threadIdx.x;
    unsigned short* er = ell + (size_t)row * ELLW;
    int c = 0;
    #pragma unroll
    for (int w = 0; w < WPR; ++w) {
        unsigned bits = bitmap[(size_t)row * WPR + w];
        while (bits) {
            int j = __ffs(bits) - 1;
            bits &= bits - 1;
            if (c < ELLW) er[c] = (unsigned short)(w * 32 + j);
            ++c;
        }
    }
    if (c > ELLW) c = ELLW;            // defensive (degree>64 ~impossible)
    dinv[row] = (c > 0) ? rsqrtf((float)c) : 0.0f;
    for (int p = c; p < ELLW; ++p) er[p] = (unsigned short)NN;  // full init
    cs[threadIdx.x] = c;
    __syncthreads();
    int q0 = threadIdx.x & ~3;
    int m = max(max(cs[q0], cs[q0 + 1]), max(cs[q0 + 2], cs[q0 + 3]));
    int cpad = (m + 3) & ~3;
    if ((threadIdx.x & 3) == 0) qcnt[row >> 2] = cpad;
}

// ---------------------------------------------------------------------------
// Fused 3-hop poly conv, one block per (graph, feature-half).
// LDS: w = dinv.*z for 512 rows x 64 features (+ zero sentinel row 512).
// Wave layout: lane = (slot=lane>>4, fq=lane&15). In each of 8 quads, slot s
// owns row 4q+s entirely; lane holds float4 of features 4fq..4fq+3.
// Gather: ds_read_b128, indices via prefetched ushort4 (4 nbrs / 8 B load).
// Per-quad counts are uniform (padded in ell_build) -> no per-lane masking.
// ---------------------------------------------------------------------------
__global__ __launch_bounds__(1024, 1) void poly_fused_kernel(
    const float* __restrict__ xin,            // [BN, NF]
    float* __restrict__ accout,               // [BN, NF]
    const unsigned short* __restrict__ ell,   // [BN][ELLW] row-major
    const int* __restrict__ qcnt,             // [BN/4] padded quad counts
    const float* __restrict__ dinv)
{
    extern __shared__ float lds[];
    float* w   = lds;                    // (NN+1)*64
    float* dsh = lds + (NN + 1) * 64;    // NN

    int b = blockIdx.x;
    int g = b >> 1;
    int h = b & 1;
    int t = threadIdx.x;
    int lane = t & 63;
    int wid  = t >> 6;                   // 0..15
    int slot = lane >> 4;                // 0..3
    int fq   = lane & 15;                // 0..15

    if (t < NN) dsh[t] = dinv[(size_t)g * NN + t];
    if (t < 64) w[NN * 64 + t] = 0.0f;   // zero sentinel row

    int rq0 = wid * 32;                  // first row of this wave
    int rown = rq0 + slot;               // own row for quad q is rown + 4q

    const float* xg = xin + (size_t)g * NN * NF + h * 64 + fq * 4;

    float4 acc[8];
    #pragma unroll
    for (int q = 0; q < 8; ++q)
        acc[q] = *(const float4*)&xg[(size_t)(rown + 4 * q) * NF];

    // preload per-quad counts (wave-uniform)
    const int* qc = qcnt + (((size_t)g * NN + rq0) >> 2);
    int cq[8];
    #pragma unroll
    for (int q = 0; q < 8; ++q)
        cq[q] = __builtin_amdgcn_readfirstlane(qc[q]);

    __syncthreads();                     // dsh + sentinel ready

    #pragma unroll
    for (int q = 0; q < 8; ++q) {
        int row = rown + 4 * q;
        float di = dsh[row];
        float4 v;
        v.x = di * acc[q].x; v.y = di * acc[q].y;
        v.z = di * acc[q].z; v.w = di * acc[q].w;
        *(float4*)&w[row * 64 + fq * 4] = v;
    }
    __syncthreads();                     // w init ready

    const unsigned short* elbase = ell + ((size_t)g * NN + rown) * ELLW;

    for (int hop = 0; hop < 3; ++hop) {
        float4 stage[8];
        #pragma unroll
        for (int q = 0; q < 8; ++q) {
            const unsigned short* el = elbase + (size_t)(4 * q) * ELLW;
            int cnt = cq[q];
            float4 s = {0.0f, 0.0f, 0.0f, 0.0f};
            if (cnt > 0) {
                ushort4 cur = *(const ushort4*)el;
                for (int p = 0; p < cnt; p += 4) {
                    ushort4 nxt = cur;
                    if (p + 4 < cnt) nxt = *(const ushort4*)(el + p + 4);
                    float4 v0 = *(const float4*)&w[(int)cur.x * 64 + fq * 4];
                    float4 v1 = *(const float4*)&w[(int)cur.y * 64 + fq * 4];
                    float4 v2 = *(const float4*)&w[(int)cur.z * 64 + fq * 4];
                    float4 v3 = *(const float4*)&w[(int)cur.w * 64 + fq * 4];
                    s.x += v0.x + v1.x + v2.x + v3.x;
                    s.y += v0.y + v1.y + v2.y + v3.y;
                    s.z += v0.z + v1.z + v2.z + v3.z;
                    s.w += v0.w + v1.w + v2.w + v3.w;
                    cur = nxt;
                }
            }
            stage[q] = s;
        }
        __syncthreads();                 // all reads of old w done
        #pragma unroll
        for (int q = 0; q < 8; ++q) {
            int row = rown + 4 * q;
            float di = dsh[row];
            float4 z;
            z.x = di * stage[q].x; z.y = di * stage[q].y;
            z.z = di * stage[q].z; z.w = di * stage[q].w;
            acc[q].x += z.x; acc[q].y += z.y;
            acc[q].z += z.z; acc[q].w += z.w;
            float4 wv;
            wv.x = di * z.x; wv.y = di * z.y;
            wv.z = di * z.z; wv.w = di * z.w;
            *(float4*)&w[row * 64 + fq * 4] = wv;
        }
        __syncthreads();                 // new w visible
    }

    float* og = accout + (size_t)g * NN * NF + h * 64 + fq * 4;
    #pragma unroll
    for (int q = 0; q < 8; ++q)
        *(float4*)&og[(size_t)(rown + 4 * q) * NF] = acc[q];
}

// ---------------------------------------------------------------------------
// GEMM: Y[65536,128] = relu(X @ W[128,128] + b)
// 512 threads, 128 rows x 128 cols per block; thread: 4 rows x 8 cols.
// X tile + W both staged in dynamic LDS (stride 132 on X breaks bank alias).
// ---------------------------------------------------------------------------
__global__ __launch_bounds__(512, 1) void gemm_bias_relu_kernel(
    const float* __restrict__ X, const float* __restrict__ W,
    const float* __restrict__ b, float* __restrict__ Y)
{
    extern __shared__ float glds[];
    float* Xs = glds;                       // 128 * XS_STRIDE
    float* Ws = glds + NF * XS_STRIDE;      // 128 * 128

    int t = threadIdx.x;
    int row0b = blockIdx.x * 128;

    // stage W (16384 floats = 4096 float4)
    for (int i = t; i < NF * NF / 4; i += 512)
        ((float4*)Ws)[i] = ((const float4*)W)[i];
    // stage X tile with padded stride
    const float* Xb = X + (size_t)row0b * NF;
    for (int i = t; i < 128 * 32; i += 512) {
        int r = i >> 5, sg = i & 31;
        *(float4*)&Xs[r * XS_STRIDE + sg * 4] =
            *(const float4*)&Xb[(size_t)r * NF + sg * 4];
    }
    __syncthreads();

    int rg = t >> 4;                        // 0..31 -> rows rg*4..rg*4+3
    int cg = t & 15;                        // cols cg*8..cg*8+7
    int col0 = cg * 8;

    float acc[4][8];
    #pragma unroll
    for (int r = 0; r < 4; ++r)
        #pragma unroll
        for (int c = 0; c < 8; ++c) acc[r][c] = 0.0f;

    for (int k = 0; k < NF; k += 4) {
        float4 xv[4];
        #pragma unroll
        for (int r = 0; r < 4; ++r)
            xv[r] = *(const float4*)&Xs[(rg * 4 + r) * XS_STRIDE + k];
        #pragma unroll
        for (int kk = 0; kk < 4; ++kk) {
            float4 w0 = *(const float4*)&Ws[(k + kk) * NF + col0];
            float4 w1 = *(const float4*)&Ws[(k + kk) * NF + col0 + 4];
            #pragma unroll
            for (int r = 0; r < 4; ++r) {
                float x = (kk == 0) ? xv[r].x : (kk == 1) ? xv[r].y
                        : (kk == 2) ? xv[r].z : xv[r].w;
                acc[r][0] += x * w0.x; acc[r][1] += x * w0.y;
                acc[r][2] += x * w0.z; acc[r][3] += x * w0.w;
                acc[r][4] += x * w1.x; acc[r][5] += x * w1.y;
                acc[r][6] += x * w1.z; acc[r][7] += x * w1.w;
            }
        }
    }

    #pragma unroll
    for (int r = 0; r < 4; ++r) {
        float out[8];
        #pragma unroll
        for (int c = 0; c < 8; ++c) {
            float v = acc[r][c] + b[col0 + c];
            out[c] = fmaxf(v, 0.0f);
        }
        float* yp = &Y[(size_t)(row0b + rg * 4 + r) * NF + col0];
        *(float4*)&yp[0] = *(float4*)&out[0];
        *(float4*)&yp[4] = *(float4*)&out[4];
    }
}

// ---------------------------------------------------------------------------
// Mean pool over nodes + 2-layer MLP readout. One block (256 thr) per graph.
// ---------------------------------------------------------------------------
__global__ __launch_bounds__(256) void pool_readout_kernel(
    const float* __restrict__ Y,
    const float* __restrict__ Wr1, const float* __restrict__ br1,
    const float* __restrict__ Wr2, const float* __restrict__ br2,
    float* __restrict__ out)
{
    __shared__ float partial[256];
    __shared__ float hsh[NF];
    __shared__ float r1[64];

    int g = blockIdx.x;
    int t = threadIdx.x;
    int f = t & (NF - 1);
    int half = t >> 7;

    const float* base = Y + (size_t)g * NN * NF;
    float s = 0.0f;
    for (int r = half * 256; r < half * 256 + 256; ++r)
        s += base[(size_t)r * NF + f];
    partial[t] = s;
    __syncthreads();

    if (t < NF) hsh[t] = (partial[t] + partial[t + NF]) * (1.0f / (float)NN);
    __syncthreads();

    if (t < 64) {
        float a = br1[t];
        #pragma unroll 8
        for (int k = 0; k < NF; ++k) a += hsh[k] * Wr1[k * 64 + t];
        r1[t] = fmaxf(a, 0.0f);
    }
    __syncthreads();

    if (t < 64) {
        float v = r1[t] * Wr2[t];
        #pragma unroll
        for (int off = 32; off; off >>= 1) v += __shfl_down(v, off);
        if (t == 0) out[g] = v + br2[0];
    }
}

// ---------------------------------------------------------------------------
extern "C" void kernel_launch(void* const* d_in, const int* in_sizes, int n_in,
                              void* d_out, int out_size, void* d_ws, size_t ws_size,
                              hipStream_t stream)
{
    const float* X    = (const float*)d_in[0];
    // d_in[1] = batch (unused; nodes already grouped per graph)
    const int*   ei   = (const int*)d_in[2];
    const float* W1   = (const float*)d_in[3];
    const float* b1   = (const float*)d_in[4];
    const float* W2   = (const float*)d_in[5];
    const float* b2   = (const float*)d_in[6];
    const float* Wr1  = (const float*)d_in[7];
    const float* br1  = (const float*)d_in[8];
    const float* Wr2  = (const float*)d_in[9];
    const float* br2  = (const float*)d_in[10];
    float* out = (float*)d_out;

    const int* src = ei;
    const int* dst = ei + NE;

    // workspace layout
    char* ws = (char*)d_ws;
    unsigned*       bitmap = (unsigned*)(ws);                        // 4 MB
    float*          dinv   = (float*)(ws + (size_t)4096 * 1024);     // 256 KB
    int*            qcnt   = (int*)(ws + (size_t)4352 * 1024);       // 64 KB
    unsigned short* ell    = (unsigned short*)(ws + (size_t)8192 * 1024); // 8 MB
    float*          buf0   = (float*)(ws + (size_t)24576 * 1024);    // 32 MB
    float*          buf1   = (float*)(ws + (size_t)57344 * 1024);    // 32 MB

    // zero bitmap (4 MB)
    hipMemsetAsync(bitmap, 0, (size_t)4096 * 1024, stream);

    build_adj_kernel<<<NE / 256, 256, 0, stream>>>(src, dst, bitmap);
    ell_build_kernel<<<BN / 256, 256, 0, stream>>>(bitmap, ell, qcnt, dinv);

    const size_t LDSSZ  = ((NN + 1) * 64 + NN) * sizeof(float);       // 133,376 B
    const size_t GLDSSZ = (NF * XS_STRIDE + NF * NF) * sizeof(float); // 133,120 B

    // ---- Layer 1
    poly_fused_kernel<<<NB * 2, 1024, LDSSZ, stream>>>(X, buf0, ell, qcnt, dinv);
    gemm_bias_relu_kernel<<<BN / 128, 512, GLDSSZ, stream>>>(buf0, W1, b1, buf1);

    // ---- Layer 2
    poly_fused_kernel<<<NB * 2, 1024, LDSSZ, stream>>>(buf1, buf0, ell, qcnt, dinv);
    gemm_bias_relu_kernel<<<BN / 128, 512, GLDSSZ, stream>>>(buf0, W2, b2, buf1);

    // ---- Pool + readout
    pool_readout_kernel<<<NB, 256, 0, stream>>>(buf1, Wr1, br1, Wr2, br2, out);
}

// Round 7
// 404.289 us; speedup vs baseline: 1.3760x; 1.0361x over previous
//
#include <hip/hip_runtime.h>
#include <hip/hip_bf16.h>

// Problem constants (match reference)
#define NB 128          // graphs
#define NN 512          // nodes per graph
#define NF 128          // feature dim
#define BN (NB*NN)      // 65536 total nodes
#define NE (BN*16)      // 1048576 edges
#define WPR 16          // bitmap words per row (512 bits / 32)
#define ELLW 64         // ELL width (max padded degree; Poisson(16) max << 64)

// ---------------------------------------------------------------------------
// Adjacency build: bitmap with set-semantics dedup (pure atomicOr)
// ---------------------------------------------------------------------------
__global__ __launch_bounds__(256) void build_adj_kernel(
    const int* __restrict__ src, const int* __restrict__ dst,
    unsigned* __restrict__ bitmap)
{
    int e = blockIdx.x * 256 + threadIdx.x;
    int s = src[e];
    int d = dst[e];
    int col = d & (NN - 1);                 // column within graph
    unsigned word = (unsigned)s * WPR + (col >> 5);
    unsigned mask = 1u << (col & 31);
    atomicOr(&bitmap[word], mask);
}

// ---------------------------------------------------------------------------
// ELL build, ROW-major ushort: ell[row][p]. Fully initializes all ELLW
// entries of every row (sentinel NN beyond the real neighbors) so no ELL
// byte is ever read uninitialized (d_ws is poisoned 0xAA between calls!).
// Also computes dinv (exact degree) and per-quad padded count via LDS max.
// ---------------------------------------------------------------------------
__global__ __launch_bounds__(256) void ell_build_kernel(
    const unsigned* __restrict__ bitmap, unsigned short* __restrict__ ell,
    int* __restrict__ qcnt, float* __restrict__ dinv)
{
    __shared__ int cs[256];
    int row = blockIdx.x * 256 + threadIdx.x;
    unsigned short* er = ell + (size_t)row * ELLW;
    int c = 0;
    #pragma unroll
    for (int w = 0; w < WPR; ++w) {
        unsigned bits = bitmap[(size_t)row * WPR + w];
        while (bits) {
            int j = __ffs(bits) - 1;
            bits &= bits - 1;
            if (c < ELLW) er[c] = (unsigned short)(w * 32 + j);
            ++c;
        }
    }
    if (c > ELLW) c = ELLW;            // defensive (degree>64 ~impossible)
    dinv[row] = (c > 0) ? rsqrtf((float)c) : 0.0f;
    for (int p = c; p < ELLW; ++p) er[p] = (unsigned short)NN;  // full init
    cs[threadIdx.x] = c;
    __syncthreads();
    int q0 = threadIdx.x & ~3;
    int m = max(max(cs[q0], cs[q0 + 1]), max(cs[q0 + 2], cs[q0 + 3]));
    int cpad = (m + 3) & ~3;
    if ((threadIdx.x & 3) == 0) qcnt[row >> 2] = cpad;
}

// ---------------------------------------------------------------------------
// Fused 3-hop poly conv, one block per (graph, feature-half). (unchanged R6)
// ---------------------------------------------------------------------------
__global__ __launch_bounds__(1024, 1) void poly_fused_kernel(
    const float* __restrict__ xin,            // [BN, NF]
    float* __restrict__ accout,               // [BN, NF]
    const unsigned short* __restrict__ ell,   // [BN][ELLW] row-major
    const int* __restrict__ qcnt,             // [BN/4] padded quad counts
    const float* __restrict__ dinv)
{
    extern __shared__ float lds[];
    float* w   = lds;                    // (NN+1)*64
    float* dsh = lds + (NN + 1) * 64;    // NN

    int b = blockIdx.x;
    int g = b >> 1;
    int h = b & 1;
    int t = threadIdx.x;
    int lane = t & 63;
    int wid  = t >> 6;                   // 0..15
    int slot = lane >> 4;                // 0..3
    int fq   = lane & 15;                // 0..15

    if (t < NN) dsh[t] = dinv[(size_t)g * NN + t];
    if (t < 64) w[NN * 64 + t] = 0.0f;   // zero sentinel row

    int rq0 = wid * 32;                  // first row of this wave
    int rown = rq0 + slot;               // own row for quad q is rown + 4q

    const float* xg = xin + (size_t)g * NN * NF + h * 64 + fq * 4;

    float4 acc[8];
    #pragma unroll
    for (int q = 0; q < 8; ++q)
        acc[q] = *(const float4*)&xg[(size_t)(rown + 4 * q) * NF];

    // preload per-quad counts (wave-uniform)
    const int* qc = qcnt + (((size_t)g * NN + rq0) >> 2);
    int cq[8];
    #pragma unroll
    for (int q = 0; q < 8; ++q)
        cq[q] = __builtin_amdgcn_readfirstlane(qc[q]);

    __syncthreads();                     // dsh + sentinel ready

    #pragma unroll
    for (int q = 0; q < 8; ++q) {
        int row = rown + 4 * q;
        float di = dsh[row];
        float4 v;
        v.x = di * acc[q].x; v.y = di * acc[q].y;
        v.z = di * acc[q].z; v.w = di * acc[q].w;
        *(float4*)&w[row * 64 + fq * 4] = v;
    }
    __syncthreads();                     // w init ready

    const unsigned short* elbase = ell + ((size_t)g * NN + rown) * ELLW;

    for (int hop = 0; hop < 3; ++hop) {
        float4 stage[8];
        #pragma unroll
        for (int q = 0; q < 8; ++q) {
            const unsigned short* el = elbase + (size_t)(4 * q) * ELLW;
            int cnt = cq[q];
            float4 s = {0.0f, 0.0f, 0.0f, 0.0f};
            if (cnt > 0) {
                ushort4 cur = *(const ushort4*)el;
                for (int p = 0; p < cnt; p += 4) {
                    ushort4 nxt = cur;
                    if (p + 4 < cnt) nxt = *(const ushort4*)(el + p + 4);
                    float4 v0 = *(const float4*)&w[(int)cur.x * 64 + fq * 4];
                    float4 v1 = *(const float4*)&w[(int)cur.y * 64 + fq * 4];
                    float4 v2 = *(const float4*)&w[(int)cur.z * 64 + fq * 4];
                    float4 v3 = *(const float4*)&w[(int)cur.w * 64 + fq * 4];
                    s.x += v0.x + v1.x + v2.x + v3.x;
                    s.y += v0.y + v1.y + v2.y + v3.y;
                    s.z += v0.z + v1.z + v2.z + v3.z;
                    s.w += v0.w + v1.w + v2.w + v3.w;
                    cur = nxt;
                }
            }
            stage[q] = s;
        }
        __syncthreads();                 // all reads of old w done
        #pragma unroll
        for (int q = 0; q < 8; ++q) {
            int row = rown + 4 * q;
            float di = dsh[row];
            float4 z;
            z.x = di * stage[q].x; z.y = di * stage[q].y;
            z.z = di * stage[q].z; z.w = di * stage[q].w;
            acc[q].x += z.x; acc[q].y += z.y;
            acc[q].z += z.z; acc[q].w += z.w;
            float4 wv;
            wv.x = di * z.x; wv.y = di * z.y;
            wv.z = di * z.z; wv.w = di * z.w;
            *(float4*)&w[row * 64 + fq * 4] = wv;
        }
        __syncthreads();                 // new w visible
    }

    float* og = accout + (size_t)g * NN * NF + h * 64 + fq * 4;
    #pragma unroll
    for (int q = 0; q < 8; ++q)
        *(float4*)&og[(size_t)(rown + 4 * q) * NF] = acc[q];
}

// ---------------------------------------------------------------------------
// GEMM: Y[65536,128] = relu(X @ W[128,128] + b), optional fused column-sum
// partials for the mean-pool (deterministic shfl tree, no atomics).
// Block: 1024 thr = 16 waves; 64 rows x 128 cols. lane = row; wave = 8 cols.
// X tile in LDS (stride 132, bank-balanced); W/bias wave-uniform -> s_load.
// ---------------------------------------------------------------------------
__global__ __launch_bounds__(1024, 1) void gemm_bias_relu_kernel(
    const float* __restrict__ X, const float* __restrict__ W,
    const float* __restrict__ b, float* __restrict__ Y,
    float* __restrict__ partial, int fuse)
{
    __shared__ float Xs[64 * 132];
    int t = threadIdx.x;
    int lane = t & 63;                       // row within tile
    int row0b = blockIdx.x * 64;

    // stage X tile: 64 rows x 128 floats (2048 float4 over 1024 threads)
    const float* Xb = X + (size_t)row0b * NF;
    #pragma unroll
    for (int i = 0; i < 2; ++i) {
        int idx = t + i * 1024;
        int r = idx >> 5, sg = idx & 31;
        *(float4*)&Xs[r * 132 + sg * 4] =
            *(const float4*)&Xb[(size_t)r * NF + sg * 4];
    }
    __syncthreads();

    int col0 = __builtin_amdgcn_readfirstlane(t >> 6) * 8;   // wave-uniform
    const float* Wc = W + col0;

    float acc[8];
    #pragma unroll
    for (int c = 0; c < 8; ++c) acc[c] = 0.0f;

    for (int k = 0; k < NF; k += 4) {
        float4 xv = *(const float4*)&Xs[lane * 132 + k];
        #pragma unroll
        for (int kk = 0; kk < 4; ++kk) {
            float4 w0 = *(const float4*)&Wc[(size_t)(k + kk) * NF];
            float4 w1 = *(const float4*)&Wc[(size_t)(k + kk) * NF + 4];
            float x = (kk == 0) ? xv.x : (kk == 1) ? xv.y
                    : (kk == 2) ? xv.z : xv.w;
            acc[0] += x * w0.x; acc[1] += x * w0.y;
            acc[2] += x * w0.z; acc[3] += x * w0.w;
            acc[4] += x * w1.x; acc[5] += x * w1.y;
            acc[6] += x * w1.z; acc[7] += x * w1.w;
        }
    }

    float4 b0 = *(const float4*)&b[col0];
    float4 b1 = *(const float4*)&b[col0 + 4];
    float o[8];
    o[0] = fmaxf(acc[0] + b0.x, 0.0f); o[1] = fmaxf(acc[1] + b0.y, 0.0f);
    o[2] = fmaxf(acc[2] + b0.z, 0.0f); o[3] = fmaxf(acc[3] + b0.w, 0.0f);
    o[4] = fmaxf(acc[4] + b1.x, 0.0f); o[5] = fmaxf(acc[5] + b1.y, 0.0f);
    o[6] = fmaxf(acc[6] + b1.z, 0.0f); o[7] = fmaxf(acc[7] + b1.w, 0.0f);

    float* yp = &Y[(size_t)(row0b + lane) * NF + col0];
    *(float4*)&yp[0] = make_float4(o[0], o[1], o[2], o[3]);
    *(float4*)&yp[4] = make_float4(o[4], o[5], o[6], o[7]);

    if (fuse) {
        // deterministic butterfly sum over the 64 rows of this tile
        #pragma unroll
        for (int c = 0; c < 8; ++c) {
            float v = o[c];
            #pragma unroll
            for (int off = 32; off; off >>= 1) v += __shfl_xor(v, off);
            if (lane == 0) partial[(size_t)blockIdx.x * NF + col0 + c] = v;
        }
    }
}

// ---------------------------------------------------------------------------
// Readout: per graph, mean-pool from gemm2 partials (8 blocks/graph) + MLP.
// 128 blocks x 128 threads.
// ---------------------------------------------------------------------------
__global__ __launch_bounds__(128) void readout_kernel(
    const float* __restrict__ partial,   // [BN/64][NF]
    const float* __restrict__ Wr1, const float* __restrict__ br1,
    const float* __restrict__ Wr2, const float* __restrict__ br2,
    float* __restrict__ out)
{
    __shared__ float hsh[NF];
    __shared__ float r1[64];

    int g = blockIdx.x;
    int t = threadIdx.x;

    const float* pg = partial + (size_t)g * 8 * NF;
    float s = 0.0f;
    #pragma unroll
    for (int j = 0; j < 8; ++j) s += pg[j * NF + t];
    hsh[t] = s * (1.0f / (float)NN);
    __syncthreads();

    if (t < 64) {
        float a = br1[t];
        #pragma unroll 8
        for (int k = 0; k < NF; ++k) a += hsh[k] * Wr1[k * 64 + t];
        r1[t] = fmaxf(a, 0.0f);
    }
    __syncthreads();

    if (t < 64) {
        float v = r1[t] * Wr2[t];
        #pragma unroll
        for (int off = 32; off; off >>= 1) v += __shfl_down(v, off);
        if (t == 0) out[g] = v + br2[0];
    }
}

// ---------------------------------------------------------------------------
extern "C" void kernel_launch(void* const* d_in, const int* in_sizes, int n_in,
                              void* d_out, int out_size, void* d_ws, size_t ws_size,
                              hipStream_t stream)
{
    const float* X    = (const float*)d_in[0];
    // d_in[1] = batch (unused; nodes already grouped per graph)
    const int*   ei   = (const int*)d_in[2];
    const float* W1   = (const float*)d_in[3];
    const float* b1   = (const float*)d_in[4];
    const float* W2   = (const float*)d_in[5];
    const float* b2   = (const float*)d_in[6];
    const float* Wr1  = (const float*)d_in[7];
    const float* br1  = (const float*)d_in[8];
    const float* Wr2  = (const float*)d_in[9];
    const float* br2  = (const float*)d_in[10];
    float* out = (float*)d_out;

    const int* src = ei;
    const int* dst = ei + NE;

    // workspace layout
    char* ws = (char*)d_ws;
    unsigned*       bitmap  = (unsigned*)(ws);                        // 4 MB
    float*          dinv    = (float*)(ws + (size_t)4096 * 1024);     // 256 KB
    int*            qcnt    = (int*)(ws + (size_t)4352 * 1024);       // 64 KB
    float*          partial = (float*)(ws + (size_t)4480 * 1024);     // 512 KB
    unsigned short* ell     = (unsigned short*)(ws + (size_t)8192 * 1024); // 8 MB
    float*          buf0    = (float*)(ws + (size_t)24576 * 1024);    // 32 MB
    float*          buf1    = (float*)(ws + (size_t)57344 * 1024);    // 32 MB

    // zero bitmap (4 MB); all other ws regions are fully written before read
    hipMemsetAsync(bitmap, 0, (size_t)4096 * 1024, stream);

    build_adj_kernel<<<NE / 256, 256, 0, stream>>>(src, dst, bitmap);
    ell_build_kernel<<<BN / 256, 256, 0, stream>>>(bitmap, ell, qcnt, dinv);

    const size_t LDSSZ = ((NN + 1) * 64 + NN) * sizeof(float);  // 133,376 B

    // ---- Layer 1
    poly_fused_kernel<<<NB * 2, 1024, LDSSZ, stream>>>(X, buf0, ell, qcnt, dinv);
    gemm_bias_relu_kernel<<<BN / 64, 1024, 0, stream>>>(buf0, W1, b1, buf1,
                                                        partial, 0);

    // ---- Layer 2 (gemm fuses deterministic pool partials)
    poly_fused_kernel<<<NB * 2, 1024, LDSSZ, stream>>>(buf1, buf0, ell, qcnt, dinv);
    gemm_bias_relu_kernel<<<BN / 64, 1024, 0, stream>>>(buf0, W2, b2, buf1,
                                                        partial, 1);

    // ---- Readout from partials
    readout_kernel<<<NB, 128, 0, stream>>>(partial, Wr1, br1, Wr2, br2, out);
}

// Round 8
// 364.007 us; speedup vs baseline: 1.5283x; 1.1107x over previous
//
#include <hip/hip_runtime.h>
#include <hip/hip_bf16.h>

// Problem constants (match reference)
#define NB 128          // graphs
#define NN 512          // nodes per graph
#define NF 128          // feature dim
#define BN (NB*NN)      // 65536 total nodes
#define NE (BN*16)      // 1048576 edges
#define WPR 16          // bitmap words per row (512 bits / 32)
#define ELLW 64         // ELL width (max padded degree; Poisson(16) max << 64)

// ---------------------------------------------------------------------------
// Adjacency build: bitmap with set-semantics dedup (pure atomicOr)
// ---------------------------------------------------------------------------
__global__ __launch_bounds__(256) void build_adj_kernel(
    const int* __restrict__ src, const int* __restrict__ dst,
    unsigned* __restrict__ bitmap)
{
    int e = blockIdx.x * 256 + threadIdx.x;
    int s = src[e];
    int d = dst[e];
    int col = d & (NN - 1);                 // column within graph
    unsigned word = (unsigned)s * WPR + (col >> 5);
    unsigned mask = 1u << (col & 31);
    atomicOr(&bitmap[word], mask);
}

// ---------------------------------------------------------------------------
// ELL build, ROW-major ushort: ell[row][p]. Rows staged in LDS then written
// out fully coalesced (16 B/lane contiguous) — the per-thread direct 2 B row
// writes were fully uncoalesced (64 cachelines per store instr).
// Fully initializes all ELLW entries (poison safety). Computes dinv + per-
// quad padded count.
// ---------------------------------------------------------------------------
__global__ __launch_bounds__(256) void ell_build_kernel(
    const unsigned* __restrict__ bitmap, unsigned short* __restrict__ ell,
    int* __restrict__ qcnt, float* __restrict__ dinv)
{
    __shared__ unsigned short els[256 * 72];   // stride 72: 144 B, 16-aligned
    __shared__ int cs[256];
    int tid = threadIdx.x;
    int row = blockIdx.x * 256 + tid;
    unsigned short* er = &els[tid * 72];
    int c = 0;
    #pragma unroll
    for (int w = 0; w < WPR; ++w) {
        unsigned bits = bitmap[(size_t)row * WPR + w];
        while (bits) {
            int j = __ffs(bits) - 1;
            bits &= bits - 1;
            if (c < ELLW) er[c] = (unsigned short)(w * 32 + j);
            ++c;
        }
    }
    if (c > ELLW) c = ELLW;            // defensive (degree>64 ~impossible)
    dinv[row] = (c > 0) ? rsqrtf((float)c) : 0.0f;
    for (int p = c; p < ELLW; ++p) er[p] = (unsigned short)NN;  // full init
    cs[tid] = c;
    __syncthreads();
    int q0 = tid & ~3;
    int m = max(max(cs[q0], cs[q0 + 1]), max(cs[q0 + 2], cs[q0 + 3]));
    int cpad = (m + 3) & ~3;
    if ((tid & 3) == 0) qcnt[row >> 2] = cpad;
    // coalesced writeout: 256 rows x 64 ushorts = 2048 x 16 B chunks
    unsigned short* outb = ell + (size_t)blockIdx.x * 256 * ELLW;
    for (int idx = tid; idx < 2048; idx += 256) {
        int r = idx >> 3, sg = idx & 7;
        uint4 v = *(const uint4*)&els[r * 72 + sg * 8];
        *(uint4*)&outb[(size_t)r * ELLW + sg * 8] = v;
    }
}

// ---------------------------------------------------------------------------
// Fused 3-hop poly conv, one block per (graph, feature-half).
// LDS: w = dinv.*z for 512 rows x 64 features (+ zero sentinel row 512).
// Wave layout: slot (lane>>4) owns row 4q+slot of each quad q; lane holds
// float4 of features. Gather via ds_read_b128, conflict-free.
// Index loads software-pipelined ACROSS quads: quad q+1's first ushort4 is
// issued before quad q's gather chain, hiding the ~200 cyc global latency.
// ---------------------------------------------------------------------------
__global__ __launch_bounds__(1024, 1) void poly_fused_kernel(
    const float* __restrict__ xin,            // [BN, NF]
    float* __restrict__ accout,               // [BN, NF]
    const unsigned short* __restrict__ ell,   // [BN][ELLW] row-major
    const int* __restrict__ qcnt,             // [BN/4] padded quad counts
    const float* __restrict__ dinv)
{
    extern __shared__ float lds[];
    float* w   = lds;                    // (NN+1)*64
    float* dsh = lds + (NN + 1) * 64;    // NN

    int b = blockIdx.x;
    int g = b >> 1;
    int h = b & 1;
    int t = threadIdx.x;
    int lane = t & 63;
    int wid  = t >> 6;                   // 0..15
    int slot = lane >> 4;                // 0..3
    int fq   = lane & 15;                // 0..15

    if (t < NN) dsh[t] = dinv[(size_t)g * NN + t];
    if (t < 64) w[NN * 64 + t] = 0.0f;   // zero sentinel row

    int rq0 = wid * 32;                  // first row of this wave
    int rown = rq0 + slot;               // own row for quad q is rown + 4q

    const float* xg = xin + (size_t)g * NN * NF + h * 64 + fq * 4;

    float4 acc[8];
    #pragma unroll
    for (int q = 0; q < 8; ++q)
        acc[q] = *(const float4*)&xg[(size_t)(rown + 4 * q) * NF];

    // preload per-quad counts (wave-uniform)
    const int* qc = qcnt + (((size_t)g * NN + rq0) >> 2);
    int cq[8];
    #pragma unroll
    for (int q = 0; q < 8; ++q)
        cq[q] = __builtin_amdgcn_readfirstlane(qc[q]);

    __syncthreads();                     // dsh + sentinel ready

    #pragma unroll
    for (int q = 0; q < 8; ++q) {
        int row = rown + 4 * q;
        float di = dsh[row];
        float4 v;
        v.x = di * acc[q].x; v.y = di * acc[q].y;
        v.z = di * acc[q].z; v.w = di * acc[q].w;
        *(float4*)&w[row * 64 + fq * 4] = v;
    }
    __syncthreads();                     // w init ready

    const unsigned short* elbase = ell + ((size_t)g * NN + rown) * ELLW;

    for (int hop = 0; hop < 3; ++hop) {
        float4 stage[8];
        ushort4 nq = *(const ushort4*)elbase;   // quad 0, batch 0
        #pragma unroll
        for (int q = 0; q < 8; ++q) {
            const unsigned short* el = elbase + (size_t)(4 * q) * ELLW;
            int cnt = cq[q];
            ushort4 cur = nq;
            if (q < 7)                   // prefetch next quad's first batch
                nq = *(const ushort4*)(elbase + (size_t)(4 * (q + 1)) * ELLW);
            float4 s = {0.0f, 0.0f, 0.0f, 0.0f};
            for (int p = 0; p < cnt; p += 4) {
                ushort4 nxt = cur;
                if (p + 4 < cnt) nxt = *(const ushort4*)(el + p + 4);
                float4 v0 = *(const float4*)&w[(int)cur.x * 64 + fq * 4];
                float4 v1 = *(const float4*)&w[(int)cur.y * 64 + fq * 4];
                float4 v2 = *(const float4*)&w[(int)cur.z * 64 + fq * 4];
                float4 v3 = *(const float4*)&w[(int)cur.w * 64 + fq * 4];
                s.x += v0.x + v1.x + v2.x + v3.x;
                s.y += v0.y + v1.y + v2.y + v3.y;
                s.z += v0.z + v1.z + v2.z + v3.z;
                s.w += v0.w + v1.w + v2.w + v3.w;
                cur = nxt;
            }
            stage[q] = s;
        }
        __syncthreads();                 // all reads of old w done
        #pragma unroll
        for (int q = 0; q < 8; ++q) {
            int row = rown + 4 * q;
            float di = dsh[row];
            float4 z;
            z.x = di * stage[q].x; z.y = di * stage[q].y;
            z.z = di * stage[q].z; z.w = di * stage[q].w;
            acc[q].x += z.x; acc[q].y += z.y;
            acc[q].z += z.z; acc[q].w += z.w;
            float4 wv;
            wv.x = di * z.x; wv.y = di * z.y;
            wv.z = di * z.z; wv.w = di * z.w;
            *(float4*)&w[row * 64 + fq * 4] = wv;
        }
        __syncthreads();                 // new w visible
    }

    float* og = accout + (size_t)g * NN * NF + h * 64 + fq * 4;
    #pragma unroll
    for (int q = 0; q < 8; ++q)
        *(float4*)&og[(size_t)(rown + 4 * q) * NF] = acc[q];
}

// ---------------------------------------------------------------------------
// GEMM: Y[65536,128] = relu(X @ W[128,128] + b), optional fused column-sum
// partials for the mean-pool (deterministic LDS tree, no atomics).
// 256 thr, 64 rows x 128 cols per block; thread = 4 rows x 8 cols.
// W in LDS (reads are 16-address wave broadcasts -> ~free). X read direct
// from global: 64-row tile = 32 KB, L1-resident, 16-way wave dedup.
// 64 KB+8 KB LDS -> 2 blocks/CU.
// ---------------------------------------------------------------------------
__global__ __launch_bounds__(256, 2) void gemm_bias_relu_kernel(
    const float* __restrict__ X, const float* __restrict__ W,
    const float* __restrict__ b, float* __restrict__ Y,
    float* __restrict__ partial, int fuse)
{
    __shared__ float Ws[NF * NF];
    __shared__ float part[16 * NF];

    int t = threadIdx.x;
    int row0b = blockIdx.x * 64;

    for (int i = t; i < NF * NF / 4; i += 256)
        ((float4*)Ws)[i] = ((const float4*)W)[i];
    __syncthreads();

    int rg = t >> 4;                        // 0..15 -> rows rg*4..rg*4+3
    int cg = t & 15;                        // cols cg*8..cg*8+7
    int col0 = cg * 8;
    int row0 = row0b + rg * 4;

    float acc[4][8];
    #pragma unroll
    for (int r = 0; r < 4; ++r)
        #pragma unroll
        for (int c = 0; c < 8; ++c) acc[r][c] = 0.0f;

    for (int k = 0; k < NF; k += 4) {
        float4 xv[4];
        #pragma unroll
        for (int r = 0; r < 4; ++r)
            xv[r] = *(const float4*)&X[(size_t)(row0 + r) * NF + k];
        #pragma unroll
        for (int kk = 0; kk < 4; ++kk) {
            float4 w0 = *(const float4*)&Ws[(k + kk) * NF + col0];
            float4 w1 = *(const float4*)&Ws[(k + kk) * NF + col0 + 4];
            #pragma unroll
            for (int r = 0; r < 4; ++r) {
                float x = (kk == 0) ? xv[r].x : (kk == 1) ? xv[r].y
                        : (kk == 2) ? xv[r].z : xv[r].w;
                acc[r][0] += x * w0.x; acc[r][1] += x * w0.y;
                acc[r][2] += x * w0.z; acc[r][3] += x * w0.w;
                acc[r][4] += x * w1.x; acc[r][5] += x * w1.y;
                acc[r][6] += x * w1.z; acc[r][7] += x * w1.w;
            }
        }
    }

    float4 b0 = *(const float4*)&b[col0];
    float4 b1 = *(const float4*)&b[col0 + 4];
    float o[4][8];
    #pragma unroll
    for (int r = 0; r < 4; ++r) {
        o[r][0] = fmaxf(acc[r][0] + b0.x, 0.0f);
        o[r][1] = fmaxf(acc[r][1] + b0.y, 0.0f);
        o[r][2] = fmaxf(acc[r][2] + b0.z, 0.0f);
        o[r][3] = fmaxf(acc[r][3] + b0.w, 0.0f);
        o[r][4] = fmaxf(acc[r][4] + b1.x, 0.0f);
        o[r][5] = fmaxf(acc[r][5] + b1.y, 0.0f);
        o[r][6] = fmaxf(acc[r][6] + b1.z, 0.0f);
        o[r][7] = fmaxf(acc[r][7] + b1.w, 0.0f);
        float* yp = &Y[(size_t)(row0 + r) * NF + col0];
        *(float4*)&yp[0] = make_float4(o[r][0], o[r][1], o[r][2], o[r][3]);
        *(float4*)&yp[4] = make_float4(o[r][4], o[r][5], o[r][6], o[r][7]);
    }

    if (fuse) {
        // deterministic per-block column sums: thread sums its 4 rows,
        // then a fixed 16-way LDS tree per column.
        #pragma unroll
        for (int c = 0; c < 8; ++c)
            part[rg * NF + col0 + c] = o[0][c] + o[1][c] + o[2][c] + o[3][c];
        __syncthreads();
        if (t < NF) {
            float s = 0.0f;
            #pragma unroll
            for (int j = 0; j < 16; ++j) s += part[j * NF + t];
            partial[(size_t)blockIdx.x * NF + t] = s;
        }
    }
}

// ---------------------------------------------------------------------------
// Readout: per graph, mean-pool from gemm2 partials (8 blocks/graph) + MLP.
// 128 blocks x 128 threads.
// ---------------------------------------------------------------------------
__global__ __launch_bounds__(128) void readout_kernel(
    const float* __restrict__ partial,   // [BN/64][NF]
    const float* __restrict__ Wr1, const float* __restrict__ br1,
    const float* __restrict__ Wr2, const float* __restrict__ br2,
    float* __restrict__ out)
{
    __shared__ float hsh[NF];
    __shared__ float r1[64];

    int g = blockIdx.x;
    int t = threadIdx.x;

    const float* pg = partial + (size_t)g * 8 * NF;
    float s = 0.0f;
    #pragma unroll
    for (int j = 0; j < 8; ++j) s += pg[j * NF + t];
    hsh[t] = s * (1.0f / (float)NN);
    __syncthreads();

    if (t < 64) {
        float a = br1[t];
        #pragma unroll 8
        for (int k = 0; k < NF; ++k) a += hsh[k] * Wr1[k * 64 + t];
        r1[t] = fmaxf(a, 0.0f);
    }
    __syncthreads();

    if (t < 64) {
        float v = r1[t] * Wr2[t];
        #pragma unroll
        for (int off = 32; off; off >>= 1) v += __shfl_down(v, off);
        if (t == 0) out[g] = v + br2[0];
    }
}

// ---------------------------------------------------------------------------
extern "C" void kernel_launch(void* const* d_in, const int* in_sizes, int n_in,
                              void* d_out, int out_size, void* d_ws, size_t ws_size,
                              hipStream_t stream)
{
    const float* X    = (const float*)d_in[0];
    // d_in[1] = batch (unused; nodes already grouped per graph)
    const int*   ei   = (const int*)d_in[2];
    const float* W1   = (const float*)d_in[3];
    const float* b1   = (const float*)d_in[4];
    const float* W2   = (const float*)d_in[5];
    const float* b2   = (const float*)d_in[6];
    const float* Wr1  = (const float*)d_in[7];
    const float* br1  = (const float*)d_in[8];
    const float* Wr2  = (const float*)d_in[9];
    const float* br2  = (const float*)d_in[10];
    float* out = (float*)d_out;

    const int* src = ei;
    const int* dst = ei + NE;

    // workspace layout
    char* ws = (char*)d_ws;
    unsigned*       bitmap  = (unsigned*)(ws);                        // 4 MB
    float*          dinv    = (float*)(ws + (size_t)4096 * 1024);     // 256 KB
    int*            qcnt    = (int*)(ws + (size_t)4352 * 1024);       // 64 KB
    float*          partial = (float*)(ws + (size_t)4480 * 1024);     // 512 KB
    unsigned short* ell     = (unsigned short*)(ws + (size_t)8192 * 1024); // 8 MB
    float*          buf0    = (float*)(ws + (size_t)24576 * 1024);    // 32 MB
    float*          buf1    = (float*)(ws + (size_t)57344 * 1024);    // 32 MB

    // zero bitmap (4 MB); all other ws regions are fully written before read
    hipMemsetAsync(bitmap, 0, (size_t)4096 * 1024, stream);

    build_adj_kernel<<<NE / 256, 256, 0, stream>>>(src, dst, bitmap);
    ell_build_kernel<<<BN / 256, 256, 0, stream>>>(bitmap, ell, qcnt, dinv);

    const size_t LDSSZ = ((NN + 1) * 64 + NN) * sizeof(float);  // 133,376 B

    // ---- Layer 1
    poly_fused_kernel<<<NB * 2, 1024, LDSSZ, stream>>>(X, buf0, ell, qcnt, dinv);
    gemm_bias_relu_kernel<<<BN / 64, 256, 0, stream>>>(buf0, W1, b1, buf1,
                                                       partial, 0);

    // ---- Layer 2 (gemm fuses deterministic pool partials)
    poly_fused_kernel<<<NB * 2, 1024, LDSSZ, stream>>>(buf1, buf0, ell, qcnt, dinv);
    gemm_bias_relu_kernel<<<BN / 64, 256, 0, stream>>>(buf0, W2, b2, buf1,
                                                       partial, 1);

    // ---- Readout from partials
    readout_kernel<<<NB, 128, 0, stream>>>(partial, Wr1, br1, Wr2, br2, out);
}

// Round 9
// 340.808 us; speedup vs baseline: 1.6323x; 1.0681x over previous
//
#include <hip/hip_runtime.h>
#include <hip/hip_bf16.h>

// Problem constants (match reference)
#define NB 128          // graphs
#define NN 512          // nodes per graph
#define NF 128          // feature dim
#define BN (NB*NN)      // 65536 total nodes
#define NE (BN*16)      // 1048576 edges
#define WPR 16          // bitmap words per row (512 bits / 32)
#define ELLW 64         // ELL width (max padded degree; Poisson(16) max << 64)

static __device__ __forceinline__ unsigned short f2bf(float f) {
    unsigned u = __float_as_uint(f);
    u += 0x7fffu + ((u >> 16) & 1u);        // round-to-nearest-even
    return (unsigned short)(u >> 16);
}

// ---------------------------------------------------------------------------
// Adjacency build: bitmap with set-semantics dedup (pure atomicOr)
// ---------------------------------------------------------------------------
__global__ __launch_bounds__(256) void build_adj_kernel(
    const int* __restrict__ src, const int* __restrict__ dst,
    unsigned* __restrict__ bitmap)
{
    int e = blockIdx.x * 256 + threadIdx.x;
    int s = src[e];
    int d = dst[e];
    int col = d & (NN - 1);                 // column within graph
    unsigned word = (unsigned)s * WPR + (col >> 5);
    unsigned mask = 1u << (col & 31);
    atomicOr(&bitmap[word], mask);
}

// ---------------------------------------------------------------------------
// ELL build, ROW-major ushort, LDS-staged coalesced writeout. Fully
// initializes all ELLW entries of every row (poison safety — d_ws is 0xAA
// between calls). Computes dinv and per-OCT (8 rows) padded count.
// ---------------------------------------------------------------------------
__global__ __launch_bounds__(256) void ell_build_kernel(
    const unsigned* __restrict__ bitmap, unsigned short* __restrict__ ell,
    int* __restrict__ ocnt, float* __restrict__ dinv)
{
    __shared__ unsigned short els[256 * 72];   // stride 72: 144 B, 16-aligned
    __shared__ int cs[256];
    int tid = threadIdx.x;
    int row = blockIdx.x * 256 + tid;
    unsigned short* er = &els[tid * 72];
    int c = 0;
    #pragma unroll
    for (int w = 0; w < WPR; ++w) {
        unsigned bits = bitmap[(size_t)row * WPR + w];
        while (bits) {
            int j = __ffs(bits) - 1;
            bits &= bits - 1;
            if (c < ELLW) er[c] = (unsigned short)(w * 32 + j);
            ++c;
        }
    }
    if (c > ELLW) c = ELLW;            // defensive (degree>64 ~impossible)
    dinv[row] = (c > 0) ? rsqrtf((float)c) : 0.0f;
    for (int p = c; p < ELLW; ++p) er[p] = (unsigned short)NN;  // full init
    cs[tid] = c;
    __syncthreads();
    int o0 = tid & ~7;
    int m = cs[o0];
    #pragma unroll
    for (int j = 1; j < 8; ++j) m = max(m, cs[o0 + j]);
    int cpad = (m + 3) & ~3;
    if ((tid & 7) == 0) ocnt[row >> 3] = cpad;
    // coalesced writeout: 256 rows x 64 ushorts = 2048 x 16 B chunks
    unsigned short* outb = ell + (size_t)blockIdx.x * 256 * ELLW;
    for (int idx = tid; idx < 2048; idx += 256) {
        int r = idx >> 3, sg = idx & 7;
        uint4 v = *(const uint4*)&els[r * 72 + sg * 8];
        *(uint4*)&outb[(size_t)r * ELLW + sg * 8] = v;
    }
}

// ---------------------------------------------------------------------------
// Fused 3-hop poly conv, one block per (graph, feature-half).
// LDS: w = bf16(dinv .* z) for 512 rows x 64 feats (128 B/row) + zero
// sentinel row. One ds_read_b128 serves 8 neighbor rows (slot=lane>>3 picks
// the row, fb=lane&7 picks 8 bf16 feats) — per-slot full 128 B bank sweep,
// the stride-1-equivalent conflict-free pattern. acc (x + z1+z2+z3) stays
// fp32 in registers; only the hop vector is bf16-rounded.
// ---------------------------------------------------------------------------
__global__ __launch_bounds__(1024, 1) void poly_fused_kernel(
    const float* __restrict__ xin,            // [BN, NF]
    float* __restrict__ accout,               // [BN, NF]
    const unsigned short* __restrict__ ell,   // [BN][ELLW] row-major
    const int* __restrict__ ocnt,             // [BN/8] padded oct counts
    const float* __restrict__ dinv)
{
    extern __shared__ float lds[];
    unsigned short* w = (unsigned short*)lds;        // (NN+1) rows * 64 bf16
    float* dsh = lds + ((NN + 1) * 64 * 2) / 4;      // NN floats (16B-aligned)

    int b = blockIdx.x;
    int g = b >> 1;
    int h = b & 1;
    int t = threadIdx.x;
    int lane = t & 63;
    int wid  = t >> 6;                   // 0..15
    int slot = lane >> 3;                // 0..7
    int fb   = lane & 7;                 // 0..7 (8 feats each)

    if (t < NN) dsh[t] = dinv[(size_t)g * NN + t];
    if (t < 64) w[NN * 64 + t] = 0;      // zero sentinel row (bf16 0)

    int rq0 = wid * 32;                  // first row of this wave
    int rown = rq0 + slot;               // own row for oct o is rown + 8*o

    const float* xg = xin + (size_t)g * NN * NF + h * 64 + fb * 8;

    // acc[o][k]: fp32, rows rown+8o, feats fb*8+k
    float acc[4][8];
    #pragma unroll
    for (int o = 0; o < 4; ++o) {
        int row = rown + 8 * o;
        float4 a0 = *(const float4*)&xg[(size_t)row * NF];
        float4 a1 = *(const float4*)&xg[(size_t)row * NF + 4];
        acc[o][0] = a0.x; acc[o][1] = a0.y; acc[o][2] = a0.z; acc[o][3] = a0.w;
        acc[o][4] = a1.x; acc[o][5] = a1.y; acc[o][6] = a1.z; acc[o][7] = a1.w;
    }

    // preload per-oct counts (wave-uniform)
    const int* oc = ocnt + (((size_t)g * NN + rq0) >> 3);
    int co[4];
    #pragma unroll
    for (int o = 0; o < 4; ++o)
        co[o] = __builtin_amdgcn_readfirstlane(oc[o]);

    __syncthreads();                     // dsh + sentinel ready

    #pragma unroll
    for (int o = 0; o < 4; ++o) {
        int row = rown + 8 * o;
        float di = dsh[row];
        unsigned pk[4];
        #pragma unroll
        for (int k = 0; k < 4; ++k) {
            unsigned lo = (unsigned)f2bf(di * acc[o][2 * k]);
            unsigned hi = (unsigned)f2bf(di * acc[o][2 * k + 1]);
            pk[k] = lo | (hi << 16);
        }
        *(uint4*)&w[row * 64 + fb * 8] = make_uint4(pk[0], pk[1], pk[2], pk[3]);
    }
    __syncthreads();                     // w init ready

    const unsigned short* elbase = ell + ((size_t)g * NN + rown) * ELLW;

    for (int hop = 0; hop < 3; ++hop) {
        float stage[4][8];
        ushort4 nq = *(const ushort4*)elbase;   // oct 0, batch 0
        #pragma unroll
        for (int o = 0; o < 4; ++o) {
            const unsigned short* el = elbase + (size_t)(8 * o) * ELLW;
            int cnt = co[o];
            ushort4 cur = nq;
            if (o < 3)                   // prefetch next oct's first batch
                nq = *(const ushort4*)(elbase + (size_t)(8 * (o + 1)) * ELLW);
            float s[8];
            #pragma unroll
            for (int k = 0; k < 8; ++k) s[k] = 0.0f;
            for (int p = 0; p < cnt; p += 4) {
                ushort4 nxt = cur;
                if (p + 4 < cnt) nxt = *(const ushort4*)(el + p + 4);
                uint4 v0 = *(const uint4*)&w[(int)cur.x * 64 + fb * 8];
                uint4 v1 = *(const uint4*)&w[(int)cur.y * 64 + fb * 8];
                uint4 v2 = *(const uint4*)&w[(int)cur.z * 64 + fb * 8];
                uint4 v3 = *(const uint4*)&w[(int)cur.w * 64 + fb * 8];
                unsigned d[4][4] = {{v0.x, v0.y, v0.z, v0.w},
                                    {v1.x, v1.y, v1.z, v1.w},
                                    {v2.x, v2.y, v2.z, v2.w},
                                    {v3.x, v3.y, v3.z, v3.w}};
                #pragma unroll
                for (int n = 0; n < 4; ++n) {
                    #pragma unroll
                    for (int k = 0; k < 4; ++k) {
                        s[2 * k]     += __uint_as_float(d[n][k] << 16);
                        s[2 * k + 1] += __uint_as_float(d[n][k] & 0xffff0000u);
                    }
                }
                cur = nxt;
            }
            #pragma unroll
            for (int k = 0; k < 8; ++k) stage[o][k] = s[k];
        }
        __syncthreads();                 // all reads of old w done
        #pragma unroll
        for (int o = 0; o < 4; ++o) {
            int row = rown + 8 * o;
            float di = dsh[row];
            unsigned pk[4];
            #pragma unroll
            for (int k = 0; k < 4; ++k) {
                float zlo = di * stage[o][2 * k];
                float zhi = di * stage[o][2 * k + 1];
                acc[o][2 * k]     += zlo;
                acc[o][2 * k + 1] += zhi;
                unsigned lo = (unsigned)f2bf(di * zlo);
                unsigned hi = (unsigned)f2bf(di * zhi);
                pk[k] = lo | (hi << 16);
            }
            *(uint4*)&w[row * 64 + fb * 8] = make_uint4(pk[0], pk[1], pk[2], pk[3]);
        }
        __syncthreads();                 // new w visible
    }

    float* og = accout + (size_t)g * NN * NF + h * 64 + fb * 8;
    #pragma unroll
    for (int o = 0; o < 4; ++o) {
        int row = rown + 8 * o;
        *(float4*)&og[(size_t)row * NF] =
            make_float4(acc[o][0], acc[o][1], acc[o][2], acc[o][3]);
        *(float4*)&og[(size_t)row * NF + 4] =
            make_float4(acc[o][4], acc[o][5], acc[o][6], acc[o][7]);
    }
}

// ---------------------------------------------------------------------------
// GEMM: Y[65536,128] = relu(X @ W[128,128] + b), optional fused column-sum
// partials for the mean-pool (deterministic LDS tree, no atomics).
// 256 thr, 64 rows x 128 cols per block; thread = 4 rows x 8 cols.
// W in LDS (16-address wave broadcasts). X direct from global (L1-resident).
// ---------------------------------------------------------------------------
__global__ __launch_bounds__(256, 2) void gemm_bias_relu_kernel(
    const float* __restrict__ X, const float* __restrict__ W,
    const float* __restrict__ b, float* __restrict__ Y,
    float* __restrict__ partial, int fuse)
{
    __shared__ float Ws[NF * NF];
    __shared__ float part[16 * NF];

    int t = threadIdx.x;
    int row0b = blockIdx.x * 64;

    for (int i = t; i < NF * NF / 4; i += 256)
        ((float4*)Ws)[i] = ((const float4*)W)[i];
    __syncthreads();

    int rg = t >> 4;                        // 0..15 -> rows rg*4..rg*4+3
    int cg = t & 15;                        // cols cg*8..cg*8+7
    int col0 = cg * 8;
    int row0 = row0b + rg * 4;

    float acc[4][8];
    #pragma unroll
    for (int r = 0; r < 4; ++r)
        #pragma unroll
        for (int c = 0; c < 8; ++c) acc[r][c] = 0.0f;

    for (int k = 0; k < NF; k += 4) {
        float4 xv[4];
        #pragma unroll
        for (int r = 0; r < 4; ++r)
            xv[r] = *(const float4*)&X[(size_t)(row0 + r) * NF + k];
        #pragma unroll
        for (int kk = 0; kk < 4; ++kk) {
            float4 w0 = *(const float4*)&Ws[(k + kk) * NF + col0];
            float4 w1 = *(const float4*)&Ws[(k + kk) * NF + col0 + 4];
            #pragma unroll
            for (int r = 0; r < 4; ++r) {
                float x = (kk == 0) ? xv[r].x : (kk == 1) ? xv[r].y
                        : (kk == 2) ? xv[r].z : xv[r].w;
                acc[r][0] += x * w0.x; acc[r][1] += x * w0.y;
                acc[r][2] += x * w0.z; acc[r][3] += x * w0.w;
                acc[r][4] += x * w1.x; acc[r][5] += x * w1.y;
                acc[r][6] += x * w1.z; acc[r][7] += x * w1.w;
            }
        }
    }

    float4 b0 = *(const float4*)&b[col0];
    float4 b1 = *(const float4*)&b[col0 + 4];
    float o[4][8];
    #pragma unroll
    for (int r = 0; r < 4; ++r) {
        o[r][0] = fmaxf(acc[r][0] + b0.x, 0.0f);
        o[r][1] = fmaxf(acc[r][1] + b0.y, 0.0f);
        o[r][2] = fmaxf(acc[r][2] + b0.z, 0.0f);
        o[r][3] = fmaxf(acc[r][3] + b0.w, 0.0f);
        o[r][4] = fmaxf(acc[r][4] + b1.x, 0.0f);
        o[r][5] = fmaxf(acc[r][5] + b1.y, 0.0f);
        o[r][6] = fmaxf(acc[r][6] + b1.z, 0.0f);
        o[r][7] = fmaxf(acc[r][7] + b1.w, 0.0f);
        float* yp = &Y[(size_t)(row0 + r) * NF + col0];
        *(float4*)&yp[0] = make_float4(o[r][0], o[r][1], o[r][2], o[r][3]);
        *(float4*)&yp[4] = make_float4(o[r][4], o[r][5], o[r][6], o[r][7]);
    }

    if (fuse) {
        #pragma unroll
        for (int c = 0; c < 8; ++c)
            part[rg * NF + col0 + c] = o[0][c] + o[1][c] + o[2][c] + o[3][c];
        __syncthreads();
        if (t < NF) {
            float s = 0.0f;
            #pragma unroll
            for (int j = 0; j < 16; ++j) s += part[j * NF + t];
            partial[(size_t)blockIdx.x * NF + t] = s;
        }
    }
}

// ---------------------------------------------------------------------------
// Readout: per graph, mean-pool from gemm2 partials (8 blocks/graph) + MLP.
// ---------------------------------------------------------------------------
__global__ __launch_bounds__(128) void readout_kernel(
    const float* __restrict__ partial,   // [BN/64][NF]
    const float* __restrict__ Wr1, const float* __restrict__ br1,
    const float* __restrict__ Wr2, const float* __restrict__ br2,
    float* __restrict__ out)
{
    __shared__ float hsh[NF];
    __shared__ float r1[64];

    int g = blockIdx.x;
    int t = threadIdx.x;

    const float* pg = partial + (size_t)g * 8 * NF;
    float s = 0.0f;
    #pragma unroll
    for (int j = 0; j < 8; ++j) s += pg[j * NF + t];
    hsh[t] = s * (1.0f / (float)NN);
    __syncthreads();

    if (t < 64) {
        float a = br1[t];
        #pragma unroll 8
        for (int k = 0; k < NF; ++k) a += hsh[k] * Wr1[k * 64 + t];
        r1[t] = fmaxf(a, 0.0f);
    }
    __syncthreads();

    if (t < 64) {
        float v = r1[t] * Wr2[t];
        #pragma unroll
        for (int off = 32; off; off >>= 1) v += __shfl_down(v, off);
        if (t == 0) out[g] = v + br2[0];
    }
}

// ---------------------------------------------------------------------------
extern "C" void kernel_launch(void* const* d_in, const int* in_sizes, int n_in,
                              void* d_out, int out_size, void* d_ws, size_t ws_size,
                              hipStream_t stream)
{
    const float* X    = (const float*)d_in[0];
    // d_in[1] = batch (unused; nodes already grouped per graph)
    const int*   ei   = (const int*)d_in[2];
    const float* W1   = (const float*)d_in[3];
    const float* b1   = (const float*)d_in[4];
    const float* W2   = (const float*)d_in[5];
    const float* b2   = (const float*)d_in[6];
    const float* Wr1  = (const float*)d_in[7];
    const float* br1  = (const float*)d_in[8];
    const float* Wr2  = (const float*)d_in[9];
    const float* br2  = (const float*)d_in[10];
    float* out = (float*)d_out;

    const int* src = ei;
    const int* dst = ei + NE;

    // workspace layout
    char* ws = (char*)d_ws;
    unsigned*       bitmap  = (unsigned*)(ws);                        // 4 MB
    float*          dinv    = (float*)(ws + (size_t)4096 * 1024);     // 256 KB
    int*            ocnt    = (int*)(ws + (size_t)4352 * 1024);       // 32 KB
    float*          partial = (float*)(ws + (size_t)4480 * 1024);     // 512 KB
    unsigned short* ell     = (unsigned short*)(ws + (size_t)8192 * 1024); // 8 MB
    float*          buf0    = (float*)(ws + (size_t)24576 * 1024);    // 32 MB
    float*          buf1    = (float*)(ws + (size_t)57344 * 1024);    // 32 MB

    // zero bitmap (4 MB); all other ws regions are fully written before read
    hipMemsetAsync(bitmap, 0, (size_t)4096 * 1024, stream);

    build_adj_kernel<<<NE / 256, 256, 0, stream>>>(src, dst, bitmap);
    ell_build_kernel<<<BN / 256, 256, 0, stream>>>(bitmap, ell, ocnt, dinv);

    // bf16 w rows (513*128 B) + dsh (512 floats)
    const size_t LDSSZ = (size_t)(NN + 1) * 64 * 2 + NN * 4;   // 67,712 B

    // ---- Layer 1
    poly_fused_kernel<<<NB * 2, 1024, LDSSZ, stream>>>(X, buf0, ell, ocnt, dinv);
    gemm_bias_relu_kernel<<<BN / 64, 256, 0, stream>>>(buf0, W1, b1, buf1,
                                                       partial, 0);

    // ---- Layer 2 (gemm fuses deterministic pool partials)
    poly_fused_kernel<<<NB * 2, 1024, LDSSZ, stream>>>(buf1, buf0, ell, ocnt, dinv);
    gemm_bias_relu_kernel<<<BN / 64, 256, 0, stream>>>(buf0, W2, b2, buf1,
                                                       partial, 1);

    // ---- Readout from partials
    readout_kernel<<<NB, 128, 0, stream>>>(partial, Wr1, br1, Wr2, br2, out);
}

// Round 10
// 296.157 us; speedup vs baseline: 1.8784x; 1.1508x over previous
//
#include <hip/hip_runtime.h>
#include <hip/hip_bf16.h>

// Problem constants (match reference)
#define NB 128          // graphs
#define NN 512          // nodes per graph
#define NF 128          // feature dim
#define BN (NB*NN)      // 65536 total nodes
#define NE (BN*16)      // 1048576 edges
#define EPG 8192        // edges per graph (N*DEG_AVG)
#define WPR 16          // bitmap words per row (512 bits / 32)
#define ELLW 64         // ELL width (max padded degree; Poisson(16) max << 64)
#define WST 72          // w row stride in ushorts (144 B) -> rotating bank phase

static __device__ __forceinline__ unsigned short f2bf(float f) {
    unsigned u = __float_as_uint(f);
    u += 0x7fffu + ((u >> 16) & 1u);        // round-to-nearest-even
    return (unsigned short)(u >> 16);
}

// ---------------------------------------------------------------------------
// Fused adjacency + ELL build, one block per graph. Edge list is graph-
// sorted (e//8192 == g), and one graph's dedup bitmap is 512x16 words =
// 32 KB -> LDS. atomicOr stays on-CU (no device-scope atomics, no global
// bitmap, no memset). ELL rows fully initialized (sentinel NN) — poison
// safe. ELL staged through LDS (reusing the bitmap space) for coalesced
// writeout, 128 rows per round.
// ---------------------------------------------------------------------------
__global__ __launch_bounds__(512) void build_ell_fused_kernel(
    const int* __restrict__ src, const int* __restrict__ dst,
    unsigned short* __restrict__ ell, int* __restrict__ ocnt,
    float* __restrict__ dinv)
{
    __shared__ unsigned bm[NN * WPR];   // 32 KB; later reused as ELL staging
    __shared__ int cs[NN];
    int g = blockIdx.x;
    int t = threadIdx.x;                // 0..511

    for (int i = t; i < NN * WPR; i += 512) bm[i] = 0u;
    __syncthreads();

    const int4* sg4 = (const int4*)(src + (size_t)g * EPG);
    const int4* dg4 = (const int4*)(dst + (size_t)g * EPG);
    for (int i = t; i < EPG / 4; i += 512) {
        int4 s4 = sg4[i];
        int4 d4 = dg4[i];
        int s, d;
        s = s4.x & (NN - 1); d = d4.x & (NN - 1);
        atomicOr(&bm[s * WPR + (d >> 5)], 1u << (d & 31));
        s = s4.y & (NN - 1); d = d4.y & (NN - 1);
        atomicOr(&bm[s * WPR + (d >> 5)], 1u << (d & 31));
        s = s4.z & (NN - 1); d = d4.z & (NN - 1);
        atomicOr(&bm[s * WPR + (d >> 5)], 1u << (d & 31));
        s = s4.w & (NN - 1); d = d4.w & (NN - 1);
        atomicOr(&bm[s * WPR + (d >> 5)], 1u << (d & 31));
    }
    __syncthreads();

    // extract this thread's row (row == t) into registers
    unsigned rw[WPR];
    #pragma unroll
    for (int w = 0; w < WPR; ++w) rw[w] = bm[t * WPR + w];
    int deg = 0;
    #pragma unroll
    for (int w = 0; w < WPR; ++w) deg += __popc(rw[w]);
    if (deg > ELLW) deg = ELLW;         // defensive
    dinv[(size_t)g * NN + t] = (deg > 0) ? rsqrtf((float)deg) : 0.0f;
    cs[t] = deg;
    __syncthreads();                    // all bm reads done; cs visible

    if ((t & 7) == 0) {
        int m = cs[t];
        #pragma unroll
        for (int j = 1; j < 8; ++j) m = max(m, cs[t + j]);
        ocnt[((size_t)g * NN + t) >> 3] = (m + 3) & ~3;
    }

    // ELL staging + coalesced writeout, 128 rows per round (18 KB <= 32 KB)
    unsigned short* els = (unsigned short*)bm;
    for (int qtr = 0; qtr < 4; ++qtr) {
        if ((t >> 7) == qtr) {
            unsigned short* er = &els[(t & 127) * WST];
            int c = 0;
            #pragma unroll
            for (int w = 0; w < WPR; ++w) {
                unsigned bits = rw[w];
                while (bits) {
                    int j = __ffs(bits) - 1;
                    bits &= bits - 1;
                    if (c < ELLW) er[c] = (unsigned short)(w * 32 + j);
                    ++c;
                }
            }
            if (c > ELLW) c = ELLW;
            for (int p = c; p < ELLW; ++p) er[p] = (unsigned short)NN;
        }
        __syncthreads();
        unsigned short* outb = ell + ((size_t)g * NN + qtr * 128) * ELLW;
        for (int idx = t; idx < 1024; idx += 512) {
            int r2 = idx >> 3, sg2 = idx & 7;
            uint4 v = *(const uint4*)&els[r2 * WST + sg2 * 8];
            *(uint4*)&outb[(size_t)r2 * ELLW + sg2 * 8] = v;
        }
        __syncthreads();
    }
}

// ---------------------------------------------------------------------------
// Fused 3-hop poly conv, one block per (graph, feature-half).
// LDS: w = bf16(dinv .* z), row stride 72 ushorts (144 B): row start bank
// rotates by 4*(row%8) -> random-neighbor gathers spread across bank phases
// (the aligned-128B layout had deterministic 8-phase collisions: 2.72M
// conflicts measured in R9). acc stays fp32 in registers.
// ---------------------------------------------------------------------------
__global__ __launch_bounds__(1024, 1) void poly_fused_kernel(
    const float* __restrict__ xin,            // [BN, NF]
    float* __restrict__ accout,               // [BN, NF]
    const unsigned short* __restrict__ ell,   // [BN][ELLW] row-major
    const int* __restrict__ ocnt,             // [BN/8] padded oct counts
    const float* __restrict__ dinv)
{
    extern __shared__ float lds[];
    unsigned short* w = (unsigned short*)lds;        // (NN+1) rows * WST
    float* dsh = lds + ((NN + 1) * WST * 2) / 4;     // NN floats

    int b = blockIdx.x;
    int g = b >> 1;
    int h = b & 1;
    int t = threadIdx.x;
    int lane = t & 63;
    int wid  = t >> 6;                   // 0..15
    int slot = lane >> 3;                // 0..7
    int fb   = lane & 7;                 // 0..7 (8 feats each)

    if (t < NN) dsh[t] = dinv[(size_t)g * NN + t];
    if (t < 64) w[NN * WST + t] = 0;     // zero sentinel row (bf16 0)

    int rq0 = wid * 32;                  // first row of this wave
    int rown = rq0 + slot;               // own row for oct o is rown + 8*o

    const float* xg = xin + (size_t)g * NN * NF + h * 64 + fb * 8;

    float acc[4][8];
    #pragma unroll
    for (int o = 0; o < 4; ++o) {
        int row = rown + 8 * o;
        float4 a0 = *(const float4*)&xg[(size_t)row * NF];
        float4 a1 = *(const float4*)&xg[(size_t)row * NF + 4];
        acc[o][0] = a0.x; acc[o][1] = a0.y; acc[o][2] = a0.z; acc[o][3] = a0.w;
        acc[o][4] = a1.x; acc[o][5] = a1.y; acc[o][6] = a1.z; acc[o][7] = a1.w;
    }

    const int* oc = ocnt + (((size_t)g * NN + rq0) >> 3);
    int co[4];
    #pragma unroll
    for (int o = 0; o < 4; ++o)
        co[o] = __builtin_amdgcn_readfirstlane(oc[o]);

    __syncthreads();                     // dsh + sentinel ready

    #pragma unroll
    for (int o = 0; o < 4; ++o) {
        int row = rown + 8 * o;
        float di = dsh[row];
        unsigned pk[4];
        #pragma unroll
        for (int k = 0; k < 4; ++k) {
            unsigned lo = (unsigned)f2bf(di * acc[o][2 * k]);
            unsigned hi = (unsigned)f2bf(di * acc[o][2 * k + 1]);
            pk[k] = lo | (hi << 16);
        }
        *(uint4*)&w[row * WST + fb * 8] = make_uint4(pk[0], pk[1], pk[2], pk[3]);
    }
    __syncthreads();                     // w init ready

    const unsigned short* elbase = ell + ((size_t)g * NN + rown) * ELLW;

    for (int hop = 0; hop < 3; ++hop) {
        float stage[4][8];
        ushort4 nq = *(const ushort4*)elbase;   // oct 0, batch 0
        #pragma unroll
        for (int o = 0; o < 4; ++o) {
            const unsigned short* el = elbase + (size_t)(8 * o) * ELLW;
            int cnt = co[o];
            ushort4 cur = nq;
            if (o < 3)                   // prefetch next oct's first batch
                nq = *(const ushort4*)(elbase + (size_t)(8 * (o + 1)) * ELLW);
            float s[8];
            #pragma unroll
            for (int k = 0; k < 8; ++k) s[k] = 0.0f;
            for (int p = 0; p < cnt; p += 4) {
                ushort4 nxt = cur;
                if (p + 4 < cnt) nxt = *(const ushort4*)(el + p + 4);
                uint4 v0 = *(const uint4*)&w[(int)cur.x * WST + fb * 8];
                uint4 v1 = *(const uint4*)&w[(int)cur.y * WST + fb * 8];
                uint4 v2 = *(const uint4*)&w[(int)cur.z * WST + fb * 8];
                uint4 v3 = *(const uint4*)&w[(int)cur.w * WST + fb * 8];
                unsigned d[4][4] = {{v0.x, v0.y, v0.z, v0.w},
                                    {v1.x, v1.y, v1.z, v1.w},
                                    {v2.x, v2.y, v2.z, v2.w},
                                    {v3.x, v3.y, v3.z, v3.w}};
                #pragma unroll
                for (int n = 0; n < 4; ++n) {
                    #pragma unroll
                    for (int k = 0; k < 4; ++k) {
                        s[2 * k]     += __uint_as_float(d[n][k] << 16);
                        s[2 * k + 1] += __uint_as_float(d[n][k] & 0xffff0000u);
                    }
                }
                cur = nxt;
            }
            #pragma unroll
            for (int k = 0; k < 8; ++k) stage[o][k] = s[k];
        }
        __syncthreads();                 // all reads of old w done
        #pragma unroll
        for (int o = 0; o < 4; ++o) {
            int row = rown + 8 * o;
            float di = dsh[row];
            unsigned pk[4];
            #pragma unroll
            for (int k = 0; k < 4; ++k) {
                float zlo = di * stage[o][2 * k];
                float zhi = di * stage[o][2 * k + 1];
                acc[o][2 * k]     += zlo;
                acc[o][2 * k + 1] += zhi;
                unsigned lo = (unsigned)f2bf(di * zlo);
                unsigned hi = (unsigned)f2bf(di * zhi);
                pk[k] = lo | (hi << 16);
            }
            *(uint4*)&w[row * WST + fb * 8] = make_uint4(pk[0], pk[1], pk[2], pk[3]);
        }
        __syncthreads();                 // new w visible
    }

    float* og = accout + (size_t)g * NN * NF + h * 64 + fb * 8;
    #pragma unroll
    for (int o = 0; o < 4; ++o) {
        int row = rown + 8 * o;
        *(float4*)&og[(size_t)row * NF] =
            make_float4(acc[o][0], acc[o][1], acc[o][2], acc[o][3]);
        *(float4*)&og[(size_t)row * NF + 4] =
            make_float4(acc[o][4], acc[o][5], acc[o][6], acc[o][7]);
    }
}

// ---------------------------------------------------------------------------
// GEMM: Y[65536,128] = relu(X @ W[128,128] + b), optional fused column-sum
// partials for the mean-pool (deterministic LDS tree, no atomics).
// ---------------------------------------------------------------------------
__global__ __launch_bounds__(256, 2) void gemm_bias_relu_kernel(
    const float* __restrict__ X, const float* __restrict__ W,
    const float* __restrict__ b, float* __restrict__ Y,
    float* __restrict__ partial, int fuse)
{
    __shared__ float Ws[NF * NF];
    __shared__ float part[16 * NF];

    int t = threadIdx.x;
    int row0b = blockIdx.x * 64;

    for (int i = t; i < NF * NF / 4; i += 256)
        ((float4*)Ws)[i] = ((const float4*)W)[i];
    __syncthreads();

    int rg = t >> 4;                        // 0..15 -> rows rg*4..rg*4+3
    int cg = t & 15;                        // cols cg*8..cg*8+7
    int col0 = cg * 8;
    int row0 = row0b + rg * 4;

    float acc[4][8];
    #pragma unroll
    for (int r = 0; r < 4; ++r)
        #pragma unroll
        for (int c = 0; c < 8; ++c) acc[r][c] = 0.0f;

    for (int k = 0; k < NF; k += 4) {
        float4 xv[4];
        #pragma unroll
        for (int r = 0; r < 4; ++r)
            xv[r] = *(const float4*)&X[(size_t)(row0 + r) * NF + k];
        #pragma unroll
        for (int kk = 0; kk < 4; ++kk) {
            float4 w0 = *(const float4*)&Ws[(k + kk) * NF + col0];
            float4 w1 = *(const float4*)&Ws[(k + kk) * NF + col0 + 4];
            #pragma unroll
            for (int r = 0; r < 4; ++r) {
                float x = (kk == 0) ? xv[r].x : (kk == 1) ? xv[r].y
                        : (kk == 2) ? xv[r].z : xv[r].w;
                acc[r][0] += x * w0.x; acc[r][1] += x * w0.y;
                acc[r][2] += x * w0.z; acc[r][3] += x * w0.w;
                acc[r][4] += x * w1.x; acc[r][5] += x * w1.y;
                acc[r][6] += x * w1.z; acc[r][7] += x * w1.w;
            }
        }
    }

    float4 b0 = *(const float4*)&b[col0];
    float4 b1 = *(const float4*)&b[col0 + 4];
    float o[4][8];
    #pragma unroll
    for (int r = 0; r < 4; ++r) {
        o[r][0] = fmaxf(acc[r][0] + b0.x, 0.0f);
        o[r][1] = fmaxf(acc[r][1] + b0.y, 0.0f);
        o[r][2] = fmaxf(acc[r][2] + b0.z, 0.0f);
        o[r][3] = fmaxf(acc[r][3] + b0.w, 0.0f);
        o[r][4] = fmaxf(acc[r][4] + b1.x, 0.0f);
        o[r][5] = fmaxf(acc[r][5] + b1.y, 0.0f);
        o[r][6] = fmaxf(acc[r][6] + b1.z, 0.0f);
        o[r][7] = fmaxf(acc[r][7] + b1.w, 0.0f);
        float* yp = &Y[(size_t)(row0 + r) * NF + col0];
        *(float4*)&yp[0] = make_float4(o[r][0], o[r][1], o[r][2], o[r][3]);
        *(float4*)&yp[4] = make_float4(o[r][4], o[r][5], o[r][6], o[r][7]);
    }

    if (fuse) {
        #pragma unroll
        for (int c = 0; c < 8; ++c)
            part[rg * NF + col0 + c] = o[0][c] + o[1][c] + o[2][c] + o[3][c];
        __syncthreads();
        if (t < NF) {
            float s = 0.0f;
            #pragma unroll
            for (int j = 0; j < 16; ++j) s += part[j * NF + t];
            partial[(size_t)blockIdx.x * NF + t] = s;
        }
    }
}

// ---------------------------------------------------------------------------
// Readout: per graph, mean-pool from gemm2 partials (8 blocks/graph) + MLP.
// ---------------------------------------------------------------------------
__global__ __launch_bounds__(128) void readout_kernel(
    const float* __restrict__ partial,   // [BN/64][NF]
    const float* __restrict__ Wr1, const float* __restrict__ br1,
    const float* __restrict__ Wr2, const float* __restrict__ br2,
    float* __restrict__ out)
{
    __shared__ float hsh[NF];
    __shared__ float r1[64];

    int g = blockIdx.x;
    int t = threadIdx.x;

    const float* pg = partial + (size_t)g * 8 * NF;
    float s = 0.0f;
    #pragma unroll
    for (int j = 0; j < 8; ++j) s += pg[j * NF + t];
    hsh[t] = s * (1.0f / (float)NN);
    __syncthreads();

    if (t < 64) {
        float a = br1[t];
        #pragma unroll 8
        for (int k = 0; k < NF; ++k) a += hsh[k] * Wr1[k * 64 + t];
        r1[t] = fmaxf(a, 0.0f);
    }
    __syncthreads();

    if (t < 64) {
        float v = r1[t] * Wr2[t];
        #pragma unroll
        for (int off = 32; off; off >>= 1) v += __shfl_down(v, off);
        if (t == 0) out[g] = v + br2[0];
    }
}

// ---------------------------------------------------------------------------
extern "C" void kernel_launch(void* const* d_in, const int* in_sizes, int n_in,
                              void* d_out, int out_size, void* d_ws, size_t ws_size,
                              hipStream_t stream)
{
    const float* X    = (const float*)d_in[0];
    // d_in[1] = batch (unused; nodes already grouped per graph)
    const int*   ei   = (const int*)d_in[2];
    const float* W1   = (const float*)d_in[3];
    const float* b1   = (const float*)d_in[4];
    const float* W2   = (const float*)d_in[5];
    const float* b2   = (const float*)d_in[6];
    const float* Wr1  = (const float*)d_in[7];
    const float* br1  = (const float*)d_in[8];
    const float* Wr2  = (const float*)d_in[9];
    const float* br2  = (const float*)d_in[10];
    float* out = (float*)d_out;

    const int* src = ei;
    const int* dst = ei + NE;

    // workspace layout
    char* ws = (char*)d_ws;
    float*          dinv    = (float*)(ws);                          // 256 KB
    int*            ocnt    = (int*)(ws + (size_t)256 * 1024);       // 32 KB
    float*          partial = (float*)(ws + (size_t)512 * 1024);     // 512 KB
    unsigned short* ell     = (unsigned short*)(ws + (size_t)1024 * 1024); // 8 MB
    float*          buf0    = (float*)(ws + (size_t)16384 * 1024);   // 32 MB
    float*          buf1    = (float*)(ws + (size_t)49152 * 1024);   // 32 MB

    // fused adjacency+ELL build (no global bitmap, no memset, LDS atomics)
    build_ell_fused_kernel<<<NB, 512, 0, stream>>>(src, dst, ell, ocnt, dinv);

    // bf16 w rows (513 * 144 B) + dsh (512 floats)
    const size_t LDSSZ = (size_t)(NN + 1) * WST * 2 + NN * 4;   // 75,920 B

    // ---- Layer 1
    poly_fused_kernel<<<NB * 2, 1024, LDSSZ, stream>>>(X, buf0, ell, ocnt, dinv);
    gemm_bias_relu_kernel<<<BN / 64, 256, 0, stream>>>(buf0, W1, b1, buf1,
                                                       partial, 0);

    // ---- Layer 2 (gemm fuses deterministic pool partials)
    poly_fused_kernel<<<NB * 2, 1024, LDSSZ, stream>>>(buf1, buf0, ell, ocnt, dinv);
    gemm_bias_relu_kernel<<<BN / 64, 256, 0, stream>>>(buf0, W2, b2, buf1,
                                                       partial, 1);

    // ---- Readout from partials
    readout_kernel<<<NB, 128, 0, stream>>>(partial, Wr1, br1, Wr2, br2, out);
}

// Round 12
// 288.275 us; speedup vs baseline: 1.9298x; 1.0273x over previous
//
#include <hip/hip_runtime.h>
#include <hip/hip_bf16.h>

// Problem constants (match reference)
#define NB 128          // graphs
#define NN 512          // nodes per graph
#define NF 128          // feature dim
#define BN (NB*NN)      // 65536 total nodes
#define NE (BN*16)      // 1048576 edges
#define EPG 8192        // edges per graph (N*DEG_AVG)
#define WPR 16          // bitmap words per row (512 bits / 32)
#define ELLW 64         // ELL width (max padded degree)
#define WST 64          // w row stride in ushorts (128 B, aligned — measured
                        // lower-conflict than 144 B rotate in R9/R10)
#define SST 72          // build-kernel ELL staging stride

static __device__ __forceinline__ unsigned short f2bf(float f) {
    unsigned u = __float_as_uint(f);
    u += 0x7fffu + ((u >> 16) & 1u);        // round-to-nearest-even
    return (unsigned short)(u >> 16);
}

// ---------------------------------------------------------------------------
// Fused adjacency + ELL build, one block per graph. LDS bitmap dedup (no
// device atomics / memset). Rows ranked by degree (deterministic brute-force
// rank); ELL stored in rank order so each oct (8 ranks) groups equal-degree
// rows -> oct padding ~mean instead of ~max (gather work x0.76).
// perm[rank] -> true row. All outputs fully initialized (poison safety).
// ---------------------------------------------------------------------------
__global__ __launch_bounds__(512) void build_ell_fused_kernel(
    const int* __restrict__ src, const int* __restrict__ dst,
    unsigned short* __restrict__ ell, int* __restrict__ ocnt,
    float* __restrict__ dinv, int* __restrict__ perm)
{
    __shared__ unsigned bm[NN * WPR];   // 32 KB; later reused as ELL staging
    __shared__ int cs[NN];              // degree by row
    __shared__ int rdeg[NN];            // degree by rank
    int g = blockIdx.x;
    int t = threadIdx.x;                // 0..511

    for (int i = t; i < NN * WPR; i += 512) bm[i] = 0u;
    __syncthreads();

    const int4* sg4 = (const int4*)(src + (size_t)g * EPG);
    const int4* dg4 = (const int4*)(dst + (size_t)g * EPG);
    for (int i = t; i < EPG / 4; i += 512) {
        int4 s4 = sg4[i];
        int4 d4 = dg4[i];
        int s, d;
        s = s4.x & (NN - 1); d = d4.x & (NN - 1);
        atomicOr(&bm[s * WPR + (d >> 5)], 1u << (d & 31));
        s = s4.y & (NN - 1); d = d4.y & (NN - 1);
        atomicOr(&bm[s * WPR + (d >> 5)], 1u << (d & 31));
        s = s4.z & (NN - 1); d = d4.z & (NN - 1);
        atomicOr(&bm[s * WPR + (d >> 5)], 1u << (d & 31));
        s = s4.w & (NN - 1); d = d4.w & (NN - 1);
        atomicOr(&bm[s * WPR + (d >> 5)], 1u << (d & 31));
    }
    __syncthreads();

    // extract this thread's row (row == t) into registers
    unsigned rw[WPR];
    #pragma unroll
    for (int w = 0; w < WPR; ++w) rw[w] = bm[t * WPR + w];
    int deg = 0;
    #pragma unroll
    for (int w = 0; w < WPR; ++w) deg += __popc(rw[w]);
    if (deg > ELLW) deg = ELLW;         // defensive
    dinv[(size_t)g * NN + t] = (deg > 0) ? rsqrtf((float)deg) : 0.0f;
    cs[t] = deg;
    __syncthreads();                    // all bm reads done; cs visible

    // deterministic rank: ascending by (deg, row). LDS reads are broadcasts.
    int rk = 0;
    for (int i = 0; i < NN; ++i) {
        int di_ = cs[i];
        rk += (di_ < deg) || (di_ == deg && i < t);
    }
    rdeg[rk] = deg;
    perm[(size_t)g * NN + rk] = t;
    __syncthreads();

    if (t < NN / 8) {
        // ascending sort: oct max = last element of the oct
        int m = rdeg[t * 8 + 7];
        ocnt[(size_t)g * (NN / 8) + t] = (m + 3) & ~3;
    }

    // ELL staging (rank order) + coalesced writeout, 128 ranks per round
    unsigned short* els = (unsigned short*)bm;
    for (int qtr = 0; qtr < 4; ++qtr) {
        if ((rk >> 7) == qtr) {
            unsigned short* er = &els[(rk & 127) * SST];
            int c = 0;
            #pragma unroll
            for (int w = 0; w < WPR; ++w) {
                unsigned bits = rw[w];
                while (bits) {
                    int j = __ffs(bits) - 1;
                    bits &= bits - 1;
                    if (c < ELLW) er[c] = (unsigned short)(w * 32 + j);
                    ++c;
                }
            }
            if (c > ELLW) c = ELLW;
            for (int p = c; p < ELLW; ++p) er[p] = (unsigned short)NN;
        }
        __syncthreads();
        unsigned short* outb = ell + ((size_t)g * NN + qtr * 128) * ELLW;
        for (int idx = t; idx < 1024; idx += 512) {
            int r2 = idx >> 3, sg2 = idx & 7;
            uint4 v = *(const uint4*)&els[r2 * SST + sg2 * 8];
            *(uint4*)&outb[(size_t)r2 * ELLW + sg2 * 8] = v;
        }
        __syncthreads();
    }
}

// ---------------------------------------------------------------------------
// Fused 3-hop poly conv, one block per (graph, feature-half).
// Rows processed in degree-rank order (perm[rank]->row): each oct has near-
// uniform degree -> minimal padding. w = bf16(dinv.*z) rows (128 B aligned),
// gather = ds_read_b128 serving 8 ranked rows. acc fp32 in registers.
// ---------------------------------------------------------------------------
__global__ __launch_bounds__(1024, 1) void poly_fused_kernel(
    const float* __restrict__ xin,            // [BN, NF]
    float* __restrict__ accout,               // [BN, NF]
    const unsigned short* __restrict__ ell,   // [BN][ELLW] rank order
    const int* __restrict__ ocnt,             // [BN/8] padded oct counts
    const float* __restrict__ dinv,
    const int* __restrict__ perm)             // [BN] rank -> row
{
    extern __shared__ float lds[];
    unsigned short* w = (unsigned short*)lds;        // (NN+1) rows * WST
    float* dsh = lds + ((NN + 1) * WST * 2) / 4;     // NN floats

    int b = blockIdx.x;
    int g = b >> 1;
    int h = b & 1;
    int t = threadIdx.x;
    int lane = t & 63;
    int wid  = t >> 6;                   // 0..15
    int slot = lane >> 3;                // 0..7
    int fb   = lane & 7;                 // 0..7 (8 feats each)

    if (t < NN) dsh[t] = dinv[(size_t)g * NN + t];
    if (t < 64) w[NN * WST + t] = 0;     // zero sentinel row (bf16 0)

    int rq0 = wid * 32;                  // first rank of this wave
    int rown = rq0 + slot;               // own rank for oct o is rown + 8*o

    // rank -> true row for this thread's 4 octs
    const int* pmg = perm + (size_t)g * NN + rown;
    int pm[4];
    #pragma unroll
    for (int o = 0; o < 4; ++o) pm[o] = pmg[8 * o];

    const float* xg = xin + (size_t)g * NN * NF + h * 64 + fb * 8;

    float acc[4][8];
    #pragma unroll
    for (int o = 0; o < 4; ++o) {
        int row = pm[o];
        float4 a0 = *(const float4*)&xg[(size_t)row * NF];
        float4 a1 = *(const float4*)&xg[(size_t)row * NF + 4];
        acc[o][0] = a0.x; acc[o][1] = a0.y; acc[o][2] = a0.z; acc[o][3] = a0.w;
        acc[o][4] = a1.x; acc[o][5] = a1.y; acc[o][6] = a1.z; acc[o][7] = a1.w;
    }

    const int* oc = ocnt + (((size_t)g * NN + rq0) >> 3);
    int co[4];
    #pragma unroll
    for (int o = 0; o < 4; ++o)
        co[o] = __builtin_amdgcn_readfirstlane(oc[o]);

    __syncthreads();                     // dsh + sentinel ready

    #pragma unroll
    for (int o = 0; o < 4; ++o) {
        int row = pm[o];
        float di = dsh[row];
        unsigned pk[4];
        #pragma unroll
        for (int k = 0; k < 4; ++k) {
            unsigned lo = (unsigned)f2bf(di * acc[o][2 * k]);
            unsigned hi = (unsigned)f2bf(di * acc[o][2 * k + 1]);
            pk[k] = lo | (hi << 16);
        }
        *(uint4*)&w[row * WST + fb * 8] = make_uint4(pk[0], pk[1], pk[2], pk[3]);
    }
    __syncthreads();                     // w init ready

    const unsigned short* elbase = ell + ((size_t)g * NN + rown) * ELLW;

    for (int hop = 0; hop < 3; ++hop) {
        float stage[4][8];
        ushort4 nq = *(const ushort4*)elbase;   // oct 0, batch 0
        #pragma unroll
        for (int o = 0; o < 4; ++o) {
            const unsigned short* el = elbase + (size_t)(8 * o) * ELLW;
            int cnt = co[o];
            ushort4 cur = nq;
            if (o < 3)                   // prefetch next oct's first batch
                nq = *(const ushort4*)(elbase + (size_t)(8 * (o + 1)) * ELLW);
            float s[8];
            #pragma unroll
            for (int k = 0; k < 8; ++k) s[k] = 0.0f;
            for (int p = 0; p < cnt; p += 4) {
                ushort4 nxt = cur;
                if (p + 4 < cnt) nxt = *(const ushort4*)(el + p + 4);
                uint4 v0 = *(const uint4*)&w[(int)cur.x * WST + fb * 8];
                uint4 v1 = *(const uint4*)&w[(int)cur.y * WST + fb * 8];
                uint4 v2 = *(const uint4*)&w[(int)cur.z * WST + fb * 8];
                uint4 v3 = *(const uint4*)&w[(int)cur.w * WST + fb * 8];
                unsigned d[4][4] = {{v0.x, v0.y, v0.z, v0.w},
                                    {v1.x, v1.y, v1.z, v1.w},
                                    {v2.x, v2.y, v2.z, v2.w},
                                    {v3.x, v3.y, v3.z, v3.w}};
                #pragma unroll
                for (int n = 0; n < 4; ++n) {
                    #pragma unroll
                    for (int k = 0; k < 4; ++k) {
                        s[2 * k]     += __uint_as_float(d[n][k] << 16);
                        s[2 * k + 1] += __uint_as_float(d[n][k] & 0xffff0000u);
                    }
                }
                cur = nxt;
            }
            #pragma unroll
            for (int k = 0; k < 8; ++k) stage[o][k] = s[k];
        }
        __syncthreads();                 // all reads of old w done
        #pragma unroll
        for (int o = 0; o < 4; ++o) {
            int row = pm[o];
            float di = dsh[row];
            unsigned pk[4];
            #pragma unroll
            for (int k = 0; k < 4; ++k) {
                float zlo = di * stage[o][2 * k];
                float zhi = di * stage[o][2 * k + 1];
                acc[o][2 * k]     += zlo;
                acc[o][2 * k + 1] += zhi;
                unsigned lo = (unsigned)f2bf(di * zlo);
                unsigned hi = (unsigned)f2bf(di * zhi);
                pk[k] = lo | (hi << 16);
            }
            *(uint4*)&w[row * WST + fb * 8] = make_uint4(pk[0], pk[1], pk[2], pk[3]);
        }
        __syncthreads();                 // new w visible
    }

    float* og = accout + (size_t)g * NN * NF + h * 64 + fb * 8;
    #pragma unroll
    for (int o = 0; o < 4; ++o) {
        int row = pm[o];
        *(float4*)&og[(size_t)row * NF] =
            make_float4(acc[o][0], acc[o][1], acc[o][2], acc[o][3]);
        *(float4*)&og[(size_t)row * NF + 4] =
            make_float4(acc[o][4], acc[o][5], acc[o][6], acc[o][7]);
    }
}

// ---------------------------------------------------------------------------
// GEMM: Y[65536,128] = relu(X @ W[128,128] + b), optional fused column-sum
// partials. 512 thr, 128 rows x 128 cols per block; thread = 4 rows x 8 cols.
// W in LDS; partial-reduce buffer ALIASES Ws (sync'd reuse) -> 64 KB LDS,
// 2 blocks/CU, 4 waves/SIMD.
// ---------------------------------------------------------------------------
__global__ __launch_bounds__(512, 2) void gemm_bias_relu_kernel(
    const float* __restrict__ X, const float* __restrict__ W,
    const float* __restrict__ b, float* __restrict__ Y,
    float* __restrict__ partial, int fuse)
{
    extern __shared__ float glds[];
    float* Ws = glds;                       // NF*NF (reused as part[] in fuse)

    int t = threadIdx.x;
    int row0b = blockIdx.x * 128;

    for (int i = t; i < NF * NF / 4; i += 512)
        ((float4*)Ws)[i] = ((const float4*)W)[i];
    __syncthreads();

    int rg = t >> 4;                        // 0..31 -> rows rg*4..rg*4+3
    int cg = t & 15;                        // cols cg*8..cg*8+7
    int col0 = cg * 8;
    int row0 = row0b + rg * 4;

    float acc[4][8];
    #pragma unroll
    for (int r = 0; r < 4; ++r)
        #pragma unroll
        for (int c = 0; c < 8; ++c) acc[r][c] = 0.0f;

    for (int k = 0; k < NF; k += 4) {
        float4 xv[4];
        #pragma unroll
        for (int r = 0; r < 4; ++r)
            xv[r] = *(const float4*)&X[(size_t)(row0 + r) * NF + k];
        #pragma unroll
        for (int kk = 0; kk < 4; ++kk) {
            float4 w0 = *(const float4*)&Ws[(k + kk) * NF + col0];
            float4 w1 = *(const float4*)&Ws[(k + kk) * NF + col0 + 4];
            #pragma unroll
            for (int r = 0; r < 4; ++r) {
                float x = (kk == 0) ? xv[r].x : (kk == 1) ? xv[r].y
                        : (kk == 2) ? xv[r].z : xv[r].w;
                acc[r][0] += x * w0.x; acc[r][1] += x * w0.y;
                acc[r][2] += x * w0.z; acc[r][3] += x * w0.w;
                acc[r][4] += x * w1.x; acc[r][5] += x * w1.y;
                acc[r][6] += x * w1.z; acc[r][7] += x * w1.w;
            }
        }
    }

    float4 b0 = *(const float4*)&b[col0];
    float4 b1 = *(const float4*)&b[col0 + 4];
    float o[4][8];
    #pragma unroll
    for (int r = 0; r < 4; ++r) {
        o[r][0] = fmaxf(acc[r][0] + b0.x, 0.0f);
        o[r][1] = fmaxf(acc[r][1] + b0.y, 0.0f);
        o[r][2] = fmaxf(acc[r][2] + b0.z, 0.0f);
        o[r][3] = fmaxf(acc[r][3] + b0.w, 0.0f);
        o[r][4] = fmaxf(acc[r][4] + b1.x, 0.0f);
        o[r][5] = fmaxf(acc[r][5] + b1.y, 0.0f);
        o[r][6] = fmaxf(acc[r][6] + b1.z, 0.0f);
        o[r][7] = fmaxf(acc[r][7] + b1.w, 0.0f);
        float* yp = &Y[(size_t)(row0 + r) * NF + col0];
        *(float4*)&yp[0] = make_float4(o[r][0], o[r][1], o[r][2], o[r][3]);
        *(float4*)&yp[4] = make_float4(o[r][4], o[r][5], o[r][6], o[r][7]);
    }

    if (fuse) {
        __syncthreads();                 // all Ws reads done; safe to reuse
        float* part = Ws;                // 32 x NF
        #pragma unroll
        for (int c = 0; c < 8; ++c)
            part[rg * NF + col0 + c] = o[0][c] + o[1][c] + o[2][c] + o[3][c];
        __syncthreads();
        if (t < NF) {
            float s = 0.0f;
            #pragma unroll
            for (int j = 0; j < 32; ++j) s += part[j * NF + t];
            partial[(size_t)blockIdx.x * NF + t] = s;
        }
    }
}

// ---------------------------------------------------------------------------
// Readout: per graph, mean-pool from gemm2 partials (4 blocks/graph) + MLP.
// ---------------------------------------------------------------------------
__global__ __launch_bounds__(128) void readout_kernel(
    const float* __restrict__ partial,   // [BN/128][NF]
    const float* __restrict__ Wr1, const float* __restrict__ br1,
    const float* __restrict__ Wr2, const float* __restrict__ br2,
    float* __restrict__ out)
{
    __shared__ float hsh[NF];
    __shared__ float r1[64];

    int g = blockIdx.x;
    int t = threadIdx.x;

    const float* pg = partial + (size_t)g * 4 * NF;
    float s = 0.0f;
    #pragma unroll
    for (int j = 0; j < 4; ++j) s += pg[j * NF + t];
    hsh[t] = s * (1.0f / (float)NN);
    __syncthreads();

    if (t < 64) {
        float a = br1[t];
        #pragma unroll 8
        for (int k = 0; k < NF; ++k) a += hsh[k] * Wr1[k * 64 + t];
        r1[t] = fmaxf(a, 0.0f);
    }
    __syncthreads();

    if (t < 64) {
        float v = r1[t] * Wr2[t];
        #pragma unroll
        for (int off = 32; off; off >>= 1) v += __shfl_down(v, off);
        if (t == 0) out[g] = v + br2[0];
    }
}

// ---------------------------------------------------------------------------
extern "C" void kernel_launch(void* const* d_in, const int* in_sizes, int n_in,
                              void* d_out, int out_size, void* d_ws, size_t ws_size,
                              hipStream_t stream)
{
    const float* X    = (const float*)d_in[0];
    // d_in[1] = batch (unused; nodes already grouped per graph)
    const int*   ei   = (const int*)d_in[2];
    const float* W1   = (const float*)d_in[3];
    const float* b1   = (const float*)d_in[4];
    const float* W2   = (const float*)d_in[5];
    const float* b2   = (const float*)d_in[6];
    const float* Wr1  = (const float*)d_in[7];
    const float* br1  = (const float*)d_in[8];
    const float* Wr2  = (const float*)d_in[9];
    const float* br2  = (const float*)d_in[10];
    float* out = (float*)d_out;

    const int* src = ei;
    const int* dst = ei + NE;

    // workspace layout
    char* ws = (char*)d_ws;
    float*          dinv    = (float*)(ws);                          // 256 KB
    int*            ocnt    = (int*)(ws + (size_t)256 * 1024);       // 32 KB
    int*            perm    = (int*)(ws + (size_t)512 * 1024);       // 256 KB
    float*          partial = (float*)(ws + (size_t)768 * 1024);     // 256 KB
    unsigned short* ell     = (unsigned short*)(ws + (size_t)1024 * 1024); // 8 MB
    float*          buf0    = (float*)(ws + (size_t)16384 * 1024);   // 32 MB
    float*          buf1    = (float*)(ws + (size_t)49152 * 1024);   // 32 MB

    // fused adjacency+ELL build with degree-rank permutation
    build_ell_fused_kernel<<<NB, 512, 0, stream>>>(src, dst, ell, ocnt, dinv,
                                                   perm);

    // bf16 w rows (513 * 128 B) + dsh (512 floats)
    const size_t LDSSZ  = (size_t)(NN + 1) * WST * 2 + NN * 4;   // 67,712 B
    const size_t GLDSSZ = (size_t)NF * NF * 4;                   // 65,536 B

    // ---- Layer 1
    poly_fused_kernel<<<NB * 2, 1024, LDSSZ, stream>>>(X, buf0, ell, ocnt,
                                                       dinv, perm);
    gemm_bias_relu_kernel<<<BN / 128, 512, GLDSSZ, stream>>>(buf0, W1, b1,
                                                             buf1, partial, 0);

    // ---- Layer 2 (gemm fuses deterministic pool partials)
    poly_fused_kernel<<<NB * 2, 1024, LDSSZ, stream>>>(buf1, buf0, ell, ocnt,
                                                       dinv, perm);
    gemm_bias_relu_kernel<<<BN / 128, 512, GLDSSZ, stream>>>(buf0, W2, b2,
                                                             buf1, partial, 1);

    // ---- Readout from partials
    readout_kernel<<<NB, 128, 0, stream>>>(partial, Wr1, br1, Wr2, br2, out);
}

// Round 13
// 268.748 us; speedup vs baseline: 2.0700x; 1.0727x over previous
//
#include <hip/hip_runtime.h>
#include <hip/hip_bf16.h>

// Problem constants (match reference)
#define NB 128          // graphs
#define NN 512          // nodes per graph
#define NF 128          // feature dim
#define BN (NB*NN)      // 65536 total nodes
#define NE (BN*16)      // 1048576 edges
#define EPG 8192        // edges per graph (N*DEG_AVG)
#define WPR 16          // bitmap words per row (512 bits / 32)
#define ELLW 64         // ELL width (max padded degree)
#define WST 64          // w row stride in ushorts (128 B aligned)
#define SST 72          // build-kernel ELL staging stride
#define WTS 136         // gemm Wt LDS stride in ushorts (272 B, 16-B aligned)

typedef short sh8 __attribute__((ext_vector_type(8)));
typedef float f32x4 __attribute__((ext_vector_type(4)));

static __device__ __forceinline__ unsigned short f2bf(float f) {
    unsigned u = __float_as_uint(f);
    u += 0x7fffu + ((u >> 16) & 1u);        // round-to-nearest-even
    return (unsigned short)(u >> 16);
}

// ---------------------------------------------------------------------------
// Fused adjacency + ELL build, one block per graph. LDS bitmap dedup.
// Rows ranked by degree; EVERYTHING downstream lives in rank space:
//  - ELL neighbor entries remapped row->rank (irank LDS lookup)
//  - dinv stored rank-indexed
//  - perm[rank]->row kept only for layer-1's X gather
// So poly's acc-writes / layer-2 reads are fully coalesced.
// All outputs fully initialized (poison safety).
// ---------------------------------------------------------------------------
__global__ __launch_bounds__(512) void build_ell_fused_kernel(
    const int* __restrict__ src, const int* __restrict__ dst,
    unsigned short* __restrict__ ell, int* __restrict__ ocnt,
    float* __restrict__ dinvr, int* __restrict__ perm)
{
    __shared__ unsigned bm[NN * WPR];   // 32 KB; later reused as ELL staging
    __shared__ int cs[NN];              // degree by row
    __shared__ int rdeg[NN];            // degree by rank
    __shared__ int irank[NN];           // row -> rank
    int g = blockIdx.x;
    int t = threadIdx.x;                // 0..511

    for (int i = t; i < NN * WPR; i += 512) bm[i] = 0u;
    __syncthreads();

    const int4* sg4 = (const int4*)(src + (size_t)g * EPG);
    const int4* dg4 = (const int4*)(dst + (size_t)g * EPG);
    for (int i = t; i < EPG / 4; i += 512) {
        int4 s4 = sg4[i];
        int4 d4 = dg4[i];
        int s, d;
        s = s4.x & (NN - 1); d = d4.x & (NN - 1);
        atomicOr(&bm[s * WPR + (d >> 5)], 1u << (d & 31));
        s = s4.y & (NN - 1); d = d4.y & (NN - 1);
        atomicOr(&bm[s * WPR + (d >> 5)], 1u << (d & 31));
        s = s4.z & (NN - 1); d = d4.z & (NN - 1);
        atomicOr(&bm[s * WPR + (d >> 5)], 1u << (d & 31));
        s = s4.w & (NN - 1); d = d4.w & (NN - 1);
        atomicOr(&bm[s * WPR + (d >> 5)], 1u << (d & 31));
    }
    __syncthreads();

    // extract this thread's row (row == t) into registers
    unsigned rw[WPR];
    #pragma unroll
    for (int w = 0; w < WPR; ++w) rw[w] = bm[t * WPR + w];
    int deg = 0;
    #pragma unroll
    for (int w = 0; w < WPR; ++w) deg += __popc(rw[w]);
    if (deg > ELLW) deg = ELLW;         // defensive
    cs[t] = deg;
    __syncthreads();                    // all bm reads done; cs visible

    // deterministic rank: ascending by (deg, row). LDS reads are broadcasts.
    int rk = 0;
    for (int i = 0; i < NN; ++i) {
        int di_ = cs[i];
        rk += (di_ < deg) || (di_ == deg && i < t);
    }
    rdeg[rk] = deg;
    irank[t] = rk;
    perm[(size_t)g * NN + rk] = t;
    dinvr[(size_t)g * NN + rk] = (deg > 0) ? rsqrtf((float)deg) : 0.0f;
    __syncthreads();

    if (t < NN / 8) {
        // ascending sort: oct max = last element of the oct
        int m = rdeg[t * 8 + 7];
        ocnt[(size_t)g * (NN / 8) + t] = (m + 3) & ~3;
    }

    // ELL staging (rank order, RANK-mapped entries) + coalesced writeout
    unsigned short* els = (unsigned short*)bm;
    for (int qtr = 0; qtr < 4; ++qtr) {
        if ((rk >> 7) == qtr) {
            unsigned short* er = &els[(rk & 127) * SST];
            int c = 0;
            #pragma unroll
            for (int w = 0; w < WPR; ++w) {
                unsigned bits = rw[w];
                while (bits) {
                    int j = __ffs(bits) - 1;
                    bits &= bits - 1;
                    if (c < ELLW) er[c] = (unsigned short)irank[w * 32 + j];
                    ++c;
                }
            }
            if (c > ELLW) c = ELLW;
            for (int p = c; p < ELLW; ++p) er[p] = (unsigned short)NN;
        }
        __syncthreads();
        unsigned short* outb = ell + ((size_t)g * NN + qtr * 128) * ELLW;
        for (int idx = t; idx < 1024; idx += 512) {
            int r2 = idx >> 3, sg2 = idx & 7;
            uint4 v = *(const uint4*)&els[r2 * SST + sg2 * 8];
            *(uint4*)&outb[(size_t)r2 * ELLW + sg2 * 8] = v;
        }
        __syncthreads();
    }
}

// ---------------------------------------------------------------------------
// Fused 3-hop poly conv in RANK space, one block per (graph, feature-half).
// ELL entries, dinv, w rows, acc-out rows all rank-indexed. Only layer 1
// (permuteIn=1) gathers X via perm; all other global IO is coalesced.
// w = bf16(dinv.*z) rows (128 B aligned); gather = ds_read_b128 serving
// 8 ranked rows. acc fp32 in registers.
// ---------------------------------------------------------------------------
__global__ __launch_bounds__(1024, 1) void poly_fused_kernel(
    const float* __restrict__ xin,            // [BN, NF]
    float* __restrict__ accout,               // [BN, NF] rank space
    const unsigned short* __restrict__ ell,   // [BN][ELLW] rank entries
    const int* __restrict__ ocnt,             // [BN/8] padded oct counts
    const float* __restrict__ dinvr,          // [BN] rank-indexed
    const int* __restrict__ perm,             // [BN] rank -> row
    int permuteIn)
{
    extern __shared__ float lds[];
    unsigned short* w = (unsigned short*)lds;        // (NN+1) rows * WST
    float* dsh = lds + ((NN + 1) * WST * 2) / 4;     // NN floats

    int b = blockIdx.x;
    int g = b >> 1;
    int h = b & 1;
    int t = threadIdx.x;
    int lane = t & 63;
    int wid  = t >> 6;                   // 0..15
    int slot = lane >> 3;                // 0..7
    int fb   = lane & 7;                 // 0..7 (8 feats each)

    if (t < NN) dsh[t] = dinvr[(size_t)g * NN + t];
    if (t < 64) w[NN * WST + t] = 0;     // zero sentinel row (bf16 0)

    int rq0 = wid * 32;                  // first rank of this wave
    int rown = rq0 + slot;               // own rank for oct o is rown + 8*o

    // input row for each oct: perm'd for layer 1, identity (coalesced) else
    int px[4];
    if (permuteIn) {
        const int* pmg = perm + (size_t)g * NN + rown;
        #pragma unroll
        for (int o = 0; o < 4; ++o) px[o] = pmg[8 * o];
    } else {
        #pragma unroll
        for (int o = 0; o < 4; ++o) px[o] = rown + 8 * o;
    }

    const float* xg = xin + (size_t)g * NN * NF + h * 64 + fb * 8;

    float acc[4][8];
    #pragma unroll
    for (int o = 0; o < 4; ++o) {
        int row = px[o];
        float4 a0 = *(const float4*)&xg[(size_t)row * NF];
        float4 a1 = *(const float4*)&xg[(size_t)row * NF + 4];
        acc[o][0] = a0.x; acc[o][1] = a0.y; acc[o][2] = a0.z; acc[o][3] = a0.w;
        acc[o][4] = a1.x; acc[o][5] = a1.y; acc[o][6] = a1.z; acc[o][7] = a1.w;
    }

    const int* oc = ocnt + (((size_t)g * NN + rq0) >> 3);
    int co[4];
    #pragma unroll
    for (int o = 0; o < 4; ++o)
        co[o] = __builtin_amdgcn_readfirstlane(oc[o]);

    __syncthreads();                     // dsh + sentinel ready

    #pragma unroll
    for (int o = 0; o < 4; ++o) {
        int rr = rown + 8 * o;           // rank position
        float di = dsh[rr];
        unsigned pk[4];
        #pragma unroll
        for (int k = 0; k < 4; ++k) {
            unsigned lo = (unsigned)f2bf(di * acc[o][2 * k]);
            unsigned hi = (unsigned)f2bf(di * acc[o][2 * k + 1]);
            pk[k] = lo | (hi << 16);
        }
        *(uint4*)&w[rr * WST + fb * 8] = make_uint4(pk[0], pk[1], pk[2], pk[3]);
    }
    __syncthreads();                     // w init ready

    const unsigned short* elbase = ell + ((size_t)g * NN + rown) * ELLW;

    for (int hop = 0; hop < 3; ++hop) {
        float stage[4][8];
        ushort4 nq = *(const ushort4*)elbase;   // oct 0, batch 0
        #pragma unroll
        for (int o = 0; o < 4; ++o) {
            const unsigned short* el = elbase + (size_t)(8 * o) * ELLW;
            int cnt = co[o];
            ushort4 cur = nq;
            if (o < 3)                   // prefetch next oct's first batch
                nq = *(const ushort4*)(elbase + (size_t)(8 * (o + 1)) * ELLW);
            float s[8];
            #pragma unroll
            for (int k = 0; k < 8; ++k) s[k] = 0.0f;
            for (int p = 0; p < cnt; p += 4) {
                ushort4 nxt = cur;
                if (p + 4 < cnt) nxt = *(const ushort4*)(el + p + 4);
                uint4 v0 = *(const uint4*)&w[(int)cur.x * WST + fb * 8];
                uint4 v1 = *(const uint4*)&w[(int)cur.y * WST + fb * 8];
                uint4 v2 = *(const uint4*)&w[(int)cur.z * WST + fb * 8];
                uint4 v3 = *(const uint4*)&w[(int)cur.w * WST + fb * 8];
                unsigned d[4][4] = {{v0.x, v0.y, v0.z, v0.w},
                                    {v1.x, v1.y, v1.z, v1.w},
                                    {v2.x, v2.y, v2.z, v2.w},
                                    {v3.x, v3.y, v3.z, v3.w}};
                #pragma unroll
                for (int n = 0; n < 4; ++n) {
                    #pragma unroll
                    for (int k = 0; k < 4; ++k) {
                        s[2 * k]     += __uint_as_float(d[n][k] << 16);
                        s[2 * k + 1] += __uint_as_float(d[n][k] & 0xffff0000u);
                    }
                }
                cur = nxt;
            }
            #pragma unroll
            for (int k = 0; k < 8; ++k) stage[o][k] = s[k];
        }
        __syncthreads();                 // all reads of old w done
        #pragma unroll
        for (int o = 0; o < 4; ++o) {
            int rr = rown + 8 * o;
            float di = dsh[rr];
            unsigned pk[4];
            #pragma unroll
            for (int k = 0; k < 4; ++k) {
                float zlo = di * stage[o][2 * k];
                float zhi = di * stage[o][2 * k + 1];
                acc[o][2 * k]     += zlo;
                acc[o][2 * k + 1] += zhi;
                unsigned lo = (unsigned)f2bf(di * zlo);
                unsigned hi = (unsigned)f2bf(di * zhi);
                pk[k] = lo | (hi << 16);
            }
            *(uint4*)&w[rr * WST + fb * 8] = make_uint4(pk[0], pk[1], pk[2], pk[3]);
        }
        __syncthreads();                 // new w visible
    }

    // coalesced write at rank positions
    float* og = accout + (size_t)g * NN * NF + h * 64 + fb * 8;
    #pragma unroll
    for (int o = 0; o < 4; ++o) {
        int rr = rown + 8 * o;
        *(float4*)&og[(size_t)rr * NF] =
            make_float4(acc[o][0], acc[o][1], acc[o][2], acc[o][3]);
        *(float4*)&og[(size_t)rr * NF + 4] =
            make_float4(acc[o][4], acc[o][5], acc[o][6], acc[o][7]);
    }
}

// ---------------------------------------------------------------------------
// MFMA bf16 GEMM: Y[65536,128] = relu(bf16(X) @ bf16(W) + b), optional fused
// deterministic mean-pool partials. 256 thr (4 waves) per 128-row block.
// Wave: 32 rows x 128 cols = 2x8 tiles of 16x16, K=128 via 4 mfma steps.
// W transposed to LDS bf16 (stride 136 ushorts = 272 B: 16-B aligned, bank
// phase rotates by 4/row -> 2 lanes/bank = free). A-frags converted from
// global fp32 in-register. Layouts per verified m89/m118:
//   A[m=lane&15][k=quad*8+j]   B[n=lane&15][k=quad*8+j]
//   C/D: col=lane&15, row=quad*4+reg
// ---------------------------------------------------------------------------
__global__ __launch_bounds__(256, 2) void gemm_bias_relu_kernel(
    const float* __restrict__ X, const float* __restrict__ W,
    const float* __restrict__ b, float* __restrict__ Y,
    float* __restrict__ partial, int fuse)
{
    __shared__ __align__(16) unsigned short Wt[NF * WTS];  // [n][k] bf16
    __shared__ float part[4 * NF];

    int t = threadIdx.x;

    // stage Wt = W^T in bf16
    for (int i = t; i < NF * NF / 4; i += 256) {
        int k = i >> 5;                 // W row
        int n4 = (i & 31) * 4;          // W col group
        float4 wv = ((const float4*)W)[i];
        Wt[(n4 + 0) * WTS + k] = f2bf(wv.x);
        Wt[(n4 + 1) * WTS + k] = f2bf(wv.y);
        Wt[(n4 + 2) * WTS + k] = f2bf(wv.z);
        Wt[(n4 + 3) * WTS + k] = f2bf(wv.w);
    }
    __syncthreads();

    int lane = t & 63;
    int wid  = t >> 6;                  // 0..3
    int quad = lane >> 4;               // 0..3
    int l16  = lane & 15;
    int rowA0 = blockIdx.x * 128 + wid * 32;

    // A fragments: af[m][kk], m in {0,1} (row halves), kk = K-step
    union { unsigned short u[8]; sh8 v; } af[2][4];
    #pragma unroll
    for (int m = 0; m < 2; ++m) {
        int r = rowA0 + m * 16 + l16;
        const float* xr = X + (size_t)r * NF + quad * 8;
        #pragma unroll
        for (int kk = 0; kk < 4; ++kk) {
            float4 x0 = *(const float4*)(xr + kk * 32);
            float4 x1 = *(const float4*)(xr + kk * 32 + 4);
            af[m][kk].u[0] = f2bf(x0.x); af[m][kk].u[1] = f2bf(x0.y);
            af[m][kk].u[2] = f2bf(x0.z); af[m][kk].u[3] = f2bf(x0.w);
            af[m][kk].u[4] = f2bf(x1.x); af[m][kk].u[5] = f2bf(x1.y);
            af[m][kk].u[6] = f2bf(x1.z); af[m][kk].u[7] = f2bf(x1.w);
        }
    }

    f32x4 acc[2][8];
    #pragma unroll
    for (int m = 0; m < 2; ++m)
        #pragma unroll
        for (int c = 0; c < 8; ++c) acc[m][c] = (f32x4){0.f, 0.f, 0.f, 0.f};

    #pragma unroll
    for (int c = 0; c < 8; ++c) {
        const unsigned short* wb = &Wt[(c * 16 + l16) * WTS + quad * 8];
        #pragma unroll
        for (int kk = 0; kk < 4; ++kk) {
            union { uint4 q; sh8 v; } bf_;
            bf_.q = *(const uint4*)(wb + kk * 32);
            acc[0][c] = __builtin_amdgcn_mfma_f32_16x16x32_bf16(
                af[0][kk].v, bf_.v, acc[0][c], 0, 0, 0);
            acc[1][c] = __builtin_amdgcn_mfma_f32_16x16x32_bf16(
                af[1][kk].v, bf_.v, acc[1][c], 0, 0, 0);
        }
    }

    float psum[8];
    #pragma unroll
    for (int c = 0; c < 8; ++c) psum[c] = 0.0f;

    #pragma unroll
    for (int c = 0; c < 8; ++c) {
        int col = c * 16 + l16;
        float bias = b[col];
        #pragma unroll
        for (int m = 0; m < 2; ++m) {
            #pragma unroll
            for (int reg = 0; reg < 4; ++reg) {
                int r = rowA0 + m * 16 + quad * 4 + reg;
                float v = fmaxf(acc[m][c][reg] + bias, 0.0f);
                Y[(size_t)r * NF + col] = v;
                psum[c] += v;
            }
        }
    }

    if (fuse) {
        // deterministic cross-quad reduction, then cross-wave LDS tree
        #pragma unroll
        for (int c = 0; c < 8; ++c) {
            float v = psum[c];
            v += __shfl_xor(v, 16);
            v += __shfl_xor(v, 32);
            if (lane < 16) part[wid * NF + c * 16 + lane] = v;
        }
        __syncthreads();
        if (t < NF) {
            float s = part[t] + part[NF + t] + part[2 * NF + t]
                    + part[3 * NF + t];
            partial[(size_t)blockIdx.x * NF + t] = s;
        }
    }
}

// ---------------------------------------------------------------------------
// Readout: per graph, mean-pool from gemm2 partials (4 blocks/graph) + MLP.
// ---------------------------------------------------------------------------
__global__ __launch_bounds__(128) void readout_kernel(
    const float* __restrict__ partial,   // [BN/128][NF]
    const float* __restrict__ Wr1, const float* __restrict__ br1,
    const float* __restrict__ Wr2, const float* __restrict__ br2,
    float* __restrict__ out)
{
    __shared__ float hsh[NF];
    __shared__ float r1[64];

    int g = blockIdx.x;
    int t = threadIdx.x;

    const float* pg = partial + (size_t)g * 4 * NF;
    float s = 0.0f;
    #pragma unroll
    for (int j = 0; j < 4; ++j) s += pg[j * NF + t];
    hsh[t] = s * (1.0f / (float)NN);
    __syncthreads();

    if (t < 64) {
        float a = br1[t];
        #pragma unroll 8
        for (int k = 0; k < NF; ++k) a += hsh[k] * Wr1[k * 64 + t];
        r1[t] = fmaxf(a, 0.0f);
    }
    __syncthreads();

    if (t < 64) {
        float v = r1[t] * Wr2[t];
        #pragma unroll
        for (int off = 32; off; off >>= 1) v += __shfl_down(v, off);
        if (t == 0) out[g] = v + br2[0];
    }
}

// ---------------------------------------------------------------------------
extern "C" void kernel_launch(void* const* d_in, const int* in_sizes, int n_in,
                              void* d_out, int out_size, void* d_ws, size_t ws_size,
                              hipStream_t stream)
{
    const float* X    = (const float*)d_in[0];
    // d_in[1] = batch (unused; nodes already grouped per graph)
    const int*   ei   = (const int*)d_in[2];
    const float* W1   = (const float*)d_in[3];
    const float* b1   = (const float*)d_in[4];
    const float* W2   = (const float*)d_in[5];
    const float* b2   = (const float*)d_in[6];
    const float* Wr1  = (const float*)d_in[7];
    const float* br1  = (const float*)d_in[8];
    const float* Wr2  = (const float*)d_in[9];
    const float* br2  = (const float*)d_in[10];
    float* out = (float*)d_out;

    const int* src = ei;
    const int* dst = ei + NE;

    // workspace layout
    char* ws = (char*)d_ws;
    float*          dinvr   = (float*)(ws);                          // 256 KB
    int*            ocnt    = (int*)(ws + (size_t)256 * 1024);       // 32 KB
    int*            perm    = (int*)(ws + (size_t)512 * 1024);       // 256 KB
    float*          partial = (float*)(ws + (size_t)768 * 1024);     // 256 KB
    unsigned short* ell     = (unsigned short*)(ws + (size_t)1024 * 1024); // 8 MB
    float*          buf0    = (float*)(ws + (size_t)16384 * 1024);   // 32 MB
    float*          buf1    = (float*)(ws + (size_t)49152 * 1024);   // 32 MB

    // fused adjacency+ELL build; rank-space outputs
    build_ell_fused_kernel<<<NB, 512, 0, stream>>>(src, dst, ell, ocnt, dinvr,
                                                   perm);

    // bf16 w rows (513 * 128 B) + dsh (512 floats)
    const size_t LDSSZ = (size_t)(NN + 1) * WST * 2 + NN * 4;   // 67,712 B

    // ---- Layer 1 (X gathered via perm into rank space)
    poly_fused_kernel<<<NB * 2, 1024, LDSSZ, stream>>>(X, buf0, ell, ocnt,
                                                       dinvr, perm, 1);
    gemm_bias_relu_kernel<<<BN / 128, 256, 0, stream>>>(buf0, W1, b1, buf1,
                                                        partial, 0);

    // ---- Layer 2 (all rank space, fully coalesced)
    poly_fused_kernel<<<NB * 2, 1024, LDSSZ, stream>>>(buf1, buf0, ell, ocnt,
                                                       dinvr, perm, 0);
    gemm_bias_relu_kernel<<<BN / 128, 256, 0, stream>>>(buf0, W2, b2, buf1,
                                                        partial, 1);

    // ---- Readout from partials
    readout_kernel<<<NB, 128, 0, stream>>>(partial, Wr1, br1, Wr2, br2, out);
}

// Round 14
// 266.307 us; speedup vs baseline: 2.0889x; 1.0092x over previous
//
#include <hip/hip_runtime.h>
#include <hip/hip_bf16.h>

// Problem constants (match reference)
#define NB 128          // graphs
#define NN 512          // nodes per graph
#define NF 128          // feature dim
#define BN (NB*NN)      // 65536 total nodes
#define NE (BN*16)      // 1048576 edges
#define EPG 8192        // edges per graph (N*DEG_AVG)
#define WPR 16          // bitmap words per row (512 bits / 32)
#define ELLW 64         // ELL width (max padded degree)
#define QST 40          // poly w row stride in ushorts (80 B -> 8 bank phases)
#define SST 72          // build-kernel ELL staging stride
#define WTS 136         // gemm Wt LDS stride in ushorts (272 B, 16-B aligned)

typedef short sh8 __attribute__((ext_vector_type(8)));
typedef float f32x4 __attribute__((ext_vector_type(4)));

static __device__ __forceinline__ unsigned short f2bf(float f) {
    unsigned u = __float_as_uint(f);
    u += 0x7fffu + ((u >> 16) & 1u);        // round-to-nearest-even
    return (unsigned short)(u >> 16);
}

// ---------------------------------------------------------------------------
// Fused adjacency + ELL build, one block per graph. LDS bitmap dedup.
// Rows ranked by degree; everything downstream lives in rank space.
// (unchanged from R13)
// ---------------------------------------------------------------------------
__global__ __launch_bounds__(512) void build_ell_fused_kernel(
    const int* __restrict__ src, const int* __restrict__ dst,
    unsigned short* __restrict__ ell, int* __restrict__ ocnt,
    float* __restrict__ dinvr, int* __restrict__ perm)
{
    __shared__ unsigned bm[NN * WPR];   // 32 KB; later reused as ELL staging
    __shared__ int cs[NN];              // degree by row
    __shared__ int rdeg[NN];            // degree by rank
    __shared__ int irank[NN];           // row -> rank
    int g = blockIdx.x;
    int t = threadIdx.x;                // 0..511

    for (int i = t; i < NN * WPR; i += 512) bm[i] = 0u;
    __syncthreads();

    const int4* sg4 = (const int4*)(src + (size_t)g * EPG);
    const int4* dg4 = (const int4*)(dst + (size_t)g * EPG);
    for (int i = t; i < EPG / 4; i += 512) {
        int4 s4 = sg4[i];
        int4 d4 = dg4[i];
        int s, d;
        s = s4.x & (NN - 1); d = d4.x & (NN - 1);
        atomicOr(&bm[s * WPR + (d >> 5)], 1u << (d & 31));
        s = s4.y & (NN - 1); d = d4.y & (NN - 1);
        atomicOr(&bm[s * WPR + (d >> 5)], 1u << (d & 31));
        s = s4.z & (NN - 1); d = d4.z & (NN - 1);
        atomicOr(&bm[s * WPR + (d >> 5)], 1u << (d & 31));
        s = s4.w & (NN - 1); d = d4.w & (NN - 1);
        atomicOr(&bm[s * WPR + (d >> 5)], 1u << (d & 31));
    }
    __syncthreads();

    // extract this thread's row (row == t) into registers
    unsigned rw[WPR];
    #pragma unroll
    for (int w = 0; w < WPR; ++w) rw[w] = bm[t * WPR + w];
    int deg = 0;
    #pragma unroll
    for (int w = 0; w < WPR; ++w) deg += __popc(rw[w]);
    if (deg > ELLW) deg = ELLW;         // defensive
    cs[t] = deg;
    __syncthreads();                    // all bm reads done; cs visible

    // deterministic rank: ascending by (deg, row). LDS reads are broadcasts.
    int rk = 0;
    for (int i = 0; i < NN; ++i) {
        int di_ = cs[i];
        rk += (di_ < deg) || (di_ == deg && i < t);
    }
    rdeg[rk] = deg;
    irank[t] = rk;
    perm[(size_t)g * NN + rk] = t;
    dinvr[(size_t)g * NN + rk] = (deg > 0) ? rsqrtf((float)deg) : 0.0f;
    __syncthreads();

    if (t < NN / 8) {
        // ascending sort: oct max = last element of the oct
        int m = rdeg[t * 8 + 7];
        ocnt[(size_t)g * (NN / 8) + t] = (m + 3) & ~3;
    }

    // ELL staging (rank order, RANK-mapped entries) + coalesced writeout
    unsigned short* els = (unsigned short*)bm;
    for (int qtr = 0; qtr < 4; ++qtr) {
        if ((rk >> 7) == qtr) {
            unsigned short* er = &els[(rk & 127) * SST];
            int c = 0;
            #pragma unroll
            for (int w = 0; w < WPR; ++w) {
                unsigned bits = rw[w];
                while (bits) {
                    int j = __ffs(bits) - 1;
                    bits &= bits - 1;
                    if (c < ELLW) er[c] = (unsigned short)irank[w * 32 + j];
                    ++c;
                }
            }
            if (c > ELLW) c = ELLW;
            for (int p = c; p < ELLW; ++p) er[p] = (unsigned short)NN;
        }
        __syncthreads();
        unsigned short* outb = ell + ((size_t)g * NN + qtr * 128) * ELLW;
        for (int idx = t; idx < 1024; idx += 512) {
            int r2 = idx >> 3, sg2 = idx & 7;
            uint4 v = *(const uint4*)&els[r2 * SST + sg2 * 8];
            *(uint4*)&outb[(size_t)r2 * ELLW + sg2 * 8] = v;
        }
        __syncthreads();
    }
}

// ---------------------------------------------------------------------------
// Fused 3-hop poly conv in RANK space, one block per (graph, feature-QUARTER).
// grid = 512 blocks of 512 thr -> 2 blocks/CU (43 KB LDS each): barriers of
// one block hide under the other block's work (R13 had 1 block/CU, latency-
// bound at 36% occupancy).
// Wave layout: slot=lane>>2 owns rows rown+16x (x=0..3); fb=lane&3 holds
// 8 feats (16 B). One ds_read_b128 = 16 rows x 64 B. w rows stride 40
// ushorts (80 B): start bank rotates through 8 phases.
// Counts per hex (16 ranks) = max of the two oct counts.
// ---------------------------------------------------------------------------
__global__ __launch_bounds__(512, 4) void poly_fused_kernel(
    const float* __restrict__ xin,            // [BN, NF]
    float* __restrict__ accout,               // [BN, NF] rank space
    const unsigned short* __restrict__ ell,   // [BN][ELLW] rank entries
    const int* __restrict__ ocnt,             // [BN/8] padded oct counts
    const float* __restrict__ dinvr,          // [BN] rank-indexed
    const int* __restrict__ perm,             // [BN] rank -> row
    int permuteIn)
{
    extern __shared__ float lds[];
    unsigned short* w = (unsigned short*)lds;        // (NN+1) rows * QST
    float* dsh = lds + ((NN + 1) * QST * 2) / 4;     // NN floats

    int b = blockIdx.x;
    int g = b >> 2;
    int q = b & 3;                       // feature quarter
    int t = threadIdx.x;                 // 0..511
    int lane = t & 63;
    int wid  = t >> 6;                   // 0..7
    int slot = lane >> 2;                // 0..15
    int fb   = lane & 3;                 // 0..3 (8 feats each)

    if (t < NN) dsh[t] = dinvr[(size_t)g * NN + t];
    if (t < QST) w[NN * QST + t] = 0;    // zero sentinel row (bf16 0)

    int rq0 = wid * 64;                  // first rank of this wave
    int rown = rq0 + slot;               // own rank for hex x is rown + 16*x

    // input row for each hex: perm'd for layer 1, identity (coalesced) else
    int px[4];
    if (permuteIn) {
        const int* pmg = perm + (size_t)g * NN + rown;
        #pragma unroll
        for (int x = 0; x < 4; ++x) px[x] = pmg[16 * x];
    } else {
        #pragma unroll
        for (int x = 0; x < 4; ++x) px[x] = rown + 16 * x;
    }

    const float* xg = xin + (size_t)g * NN * NF + q * 32 + fb * 8;

    float acc[4][8];
    #pragma unroll
    for (int x = 0; x < 4; ++x) {
        int row = px[x];
        float4 a0 = *(const float4*)&xg[(size_t)row * NF];
        float4 a1 = *(const float4*)&xg[(size_t)row * NF + 4];
        acc[x][0] = a0.x; acc[x][1] = a0.y; acc[x][2] = a0.z; acc[x][3] = a0.w;
        acc[x][4] = a1.x; acc[x][5] = a1.y; acc[x][6] = a1.z; acc[x][7] = a1.w;
    }

    // per-hex counts = max of the hex's two oct counts (wave-uniform)
    const int* oc = ocnt + (((size_t)g * NN + rq0) >> 3);
    int co[4];
    #pragma unroll
    for (int x = 0; x < 4; ++x)
        co[x] = __builtin_amdgcn_readfirstlane(max(oc[2 * x], oc[2 * x + 1]));

    __syncthreads();                     // dsh + sentinel ready

    #pragma unroll
    for (int x = 0; x < 4; ++x) {
        int rr = rown + 16 * x;          // rank position
        float di = dsh[rr];
        unsigned pk[4];
        #pragma unroll
        for (int k = 0; k < 4; ++k) {
            unsigned lo = (unsigned)f2bf(di * acc[x][2 * k]);
            unsigned hi = (unsigned)f2bf(di * acc[x][2 * k + 1]);
            pk[k] = lo | (hi << 16);
        }
        *(uint4*)&w[rr * QST + fb * 8] = make_uint4(pk[0], pk[1], pk[2], pk[3]);
    }
    __syncthreads();                     // w init ready

    const unsigned short* elbase = ell + ((size_t)g * NN + rown) * ELLW;

    for (int hop = 0; hop < 3; ++hop) {
        float stage[4][8];
        ushort4 nq = *(const ushort4*)elbase;   // hex 0, batch 0
        #pragma unroll
        for (int x = 0; x < 4; ++x) {
            const unsigned short* el = elbase + (size_t)(16 * x) * ELLW;
            int cnt = co[x];
            ushort4 cur = nq;
            if (x < 3)                   // prefetch next hex's first batch
                nq = *(const ushort4*)(elbase + (size_t)(16 * (x + 1)) * ELLW);
            float s[8];
            #pragma unroll
            for (int k = 0; k < 8; ++k) s[k] = 0.0f;
            for (int p = 0; p < cnt; p += 4) {
                ushort4 nxt = cur;
                if (p + 4 < cnt) nxt = *(const ushort4*)(el + p + 4);
                uint4 v0 = *(const uint4*)&w[(int)cur.x * QST + fb * 8];
                uint4 v1 = *(const uint4*)&w[(int)cur.y * QST + fb * 8];
                uint4 v2 = *(const uint4*)&w[(int)cur.z * QST + fb * 8];
                uint4 v3 = *(const uint4*)&w[(int)cur.w * QST + fb * 8];
                unsigned d[4][4] = {{v0.x, v0.y, v0.z, v0.w},
                                    {v1.x, v1.y, v1.z, v1.w},
                                    {v2.x, v2.y, v2.z, v2.w},
                                    {v3.x, v3.y, v3.z, v3.w}};
                #pragma unroll
                for (int n = 0; n < 4; ++n) {
                    #pragma unroll
                    for (int k = 0; k < 4; ++k) {
                        s[2 * k]     += __uint_as_float(d[n][k] << 16);
                        s[2 * k + 1] += __uint_as_float(d[n][k] & 0xffff0000u);
                    }
                }
                cur = nxt;
            }
            #pragma unroll
            for (int k = 0; k < 8; ++k) stage[x][k] = s[k];
        }
        __syncthreads();                 // all reads of old w done
        #pragma unroll
        for (int x = 0; x < 4; ++x) {
            int rr = rown + 16 * x;
            float di = dsh[rr];
            unsigned pk[4];
            #pragma unroll
            for (int k = 0; k < 4; ++k) {
                float zlo = di * stage[x][2 * k];
                float zhi = di * stage[x][2 * k + 1];
                acc[x][2 * k]     += zlo;
                acc[x][2 * k + 1] += zhi;
                unsigned lo = (unsigned)f2bf(di * zlo);
                unsigned hi = (unsigned)f2bf(di * zhi);
                pk[k] = lo | (hi << 16);
            }
            *(uint4*)&w[rr * QST + fb * 8] = make_uint4(pk[0], pk[1], pk[2], pk[3]);
        }
        __syncthreads();                 // new w visible
    }

    // coalesced write at rank positions
    float* og = accout + (size_t)g * NN * NF + q * 32 + fb * 8;
    #pragma unroll
    for (int x = 0; x < 4; ++x) {
        int rr = rown + 16 * x;
        *(float4*)&og[(size_t)rr * NF] =
            make_float4(acc[x][0], acc[x][1], acc[x][2], acc[x][3]);
        *(float4*)&og[(size_t)rr * NF + 4] =
            make_float4(acc[x][4], acc[x][5], acc[x][6], acc[x][7]);
    }
}

// ---------------------------------------------------------------------------
// MFMA bf16 GEMM: Y[65536,128] = relu(bf16(X) @ bf16(W) + b), optional fused
// deterministic mean-pool partials. (unchanged from R13)
// ---------------------------------------------------------------------------
__global__ __launch_bounds__(256, 2) void gemm_bias_relu_kernel(
    const float* __restrict__ X, const float* __restrict__ W,
    const float* __restrict__ b, float* __restrict__ Y,
    float* __restrict__ partial, int fuse)
{
    __shared__ __align__(16) unsigned short Wt[NF * WTS];  // [n][k] bf16
    __shared__ float part[4 * NF];

    int t = threadIdx.x;

    // stage Wt = W^T in bf16
    for (int i = t; i < NF * NF / 4; i += 256) {
        int k = i >> 5;                 // W row
        int n4 = (i & 31) * 4;          // W col group
        float4 wv = ((const float4*)W)[i];
        Wt[(n4 + 0) * WTS + k] = f2bf(wv.x);
        Wt[(n4 + 1) * WTS + k] = f2bf(wv.y);
        Wt[(n4 + 2) * WTS + k] = f2bf(wv.z);
        Wt[(n4 + 3) * WTS + k] = f2bf(wv.w);
    }
    __syncthreads();

    int lane = t & 63;
    int wid  = t >> 6;                  // 0..3
    int quad = lane >> 4;               // 0..3
    int l16  = lane & 15;
    int rowA0 = blockIdx.x * 128 + wid * 32;

    // A fragments: af[m][kk], m in {0,1} (row halves), kk = K-step
    union { unsigned short u[8]; sh8 v; } af[2][4];
    #pragma unroll
    for (int m = 0; m < 2; ++m) {
        int r = rowA0 + m * 16 + l16;
        const float* xr = X + (size_t)r * NF + quad * 8;
        #pragma unroll
        for (int kk = 0; kk < 4; ++kk) {
            float4 x0 = *(const float4*)(xr + kk * 32);
            float4 x1 = *(const float4*)(xr + kk * 32 + 4);
            af[m][kk].u[0] = f2bf(x0.x); af[m][kk].u[1] = f2bf(x0.y);
            af[m][kk].u[2] = f2bf(x0.z); af[m][kk].u[3] = f2bf(x0.w);
            af[m][kk].u[4] = f2bf(x1.x); af[m][kk].u[5] = f2bf(x1.y);
            af[m][kk].u[6] = f2bf(x1.z); af[m][kk].u[7] = f2bf(x1.w);
        }
    }

    f32x4 acc[2][8];
    #pragma unroll
    for (int m = 0; m < 2; ++m)
        #pragma unroll
        for (int c = 0; c < 8; ++c) acc[m][c] = (f32x4){0.f, 0.f, 0.f, 0.f};

    #pragma unroll
    for (int c = 0; c < 8; ++c) {
        const unsigned short* wb = &Wt[(c * 16 + l16) * WTS + quad * 8];
        #pragma unroll
        for (int kk = 0; kk < 4; ++kk) {
            union { uint4 q; sh8 v; } bf_;
            bf_.q = *(const uint4*)(wb + kk * 32);
            acc[0][c] = __builtin_amdgcn_mfma_f32_16x16x32_bf16(
                af[0][kk].v, bf_.v, acc[0][c], 0, 0, 0);
            acc[1][c] = __builtin_amdgcn_mfma_f32_16x16x32_bf16(
                af[1][kk].v, bf_.v, acc[1][c], 0, 0, 0);
        }
    }

    float psum[8];
    #pragma unroll
    for (int c = 0; c < 8; ++c) psum[c] = 0.0f;

    #pragma unroll
    for (int c = 0; c < 8; ++c) {
        int col = c * 16 + l16;
        float bias = b[col];
        #pragma unroll
        for (int m = 0; m < 2; ++m) {
            #pragma unroll
            for (int reg = 0; reg < 4; ++reg) {
                int r = rowA0 + m * 16 + quad * 4 + reg;
                float v = fmaxf(acc[m][c][reg] + bias, 0.0f);
                Y[(size_t)r * NF + col] = v;
                psum[c] += v;
            }
        }
    }

    if (fuse) {
        // deterministic cross-quad reduction, then cross-wave LDS tree
        #pragma unroll
        for (int c = 0; c < 8; ++c) {
            float v = psum[c];
            v += __shfl_xor(v, 16);
            v += __shfl_xor(v, 32);
            if (lane < 16) part[wid * NF + c * 16 + lane] = v;
        }
        __syncthreads();
        if (t < NF) {
            float s = part[t] + part[NF + t] + part[2 * NF + t]
                    + part[3 * NF + t];
            partial[(size_t)blockIdx.x * NF + t] = s;
        }
    }
}

// ---------------------------------------------------------------------------
// Readout: per graph, mean-pool from gemm2 partials (4 blocks/graph) + MLP.
// ---------------------------------------------------------------------------
__global__ __launch_bounds__(128) void readout_kernel(
    const float* __restrict__ partial,   // [BN/128][NF]
    const float* __restrict__ Wr1, const float* __restrict__ br1,
    const float* __restrict__ Wr2, const float* __restrict__ br2,
    float* __restrict__ out)
{
    __shared__ float hsh[NF];
    __shared__ float r1[64];

    int g = blockIdx.x;
    int t = threadIdx.x;

    const float* pg = partial + (size_t)g * 4 * NF;
    float s = 0.0f;
    #pragma unroll
    for (int j = 0; j < 4; ++j) s += pg[j * NF + t];
    hsh[t] = s * (1.0f / (float)NN);
    __syncthreads();

    if (t < 64) {
        float a = br1[t];
        #pragma unroll 8
        for (int k = 0; k < NF; ++k) a += hsh[k] * Wr1[k * 64 + t];
        r1[t] = fmaxf(a, 0.0f);
    }
    __syncthreads();

    if (t < 64) {
        float v = r1[t] * Wr2[t];
        #pragma unroll
        for (int off = 32; off; off >>= 1) v += __shfl_down(v, off);
        if (t == 0) out[g] = v + br2[0];
    }
}

// ---------------------------------------------------------------------------
extern "C" void kernel_launch(void* const* d_in, const int* in_sizes, int n_in,
                              void* d_out, int out_size, void* d_ws, size_t ws_size,
                              hipStream_t stream)
{
    const float* X    = (const float*)d_in[0];
    // d_in[1] = batch (unused; nodes already grouped per graph)
    const int*   ei   = (const int*)d_in[2];
    const float* W1   = (const float*)d_in[3];
    const float* b1   = (const float*)d_in[4];
    const float* W2   = (const float*)d_in[5];
    const float* b2   = (const float*)d_in[6];
    const float* Wr1  = (const float*)d_in[7];
    const float* br1  = (const float*)d_in[8];
    const float* Wr2  = (const float*)d_in[9];
    const float* br2  = (const float*)d_in[10];
    float* out = (float*)d_out;

    const int* src = ei;
    const int* dst = ei + NE;

    // workspace layout
    char* ws = (char*)d_ws;
    float*          dinvr   = (float*)(ws);                          // 256 KB
    int*            ocnt    = (int*)(ws + (size_t)256 * 1024);       // 32 KB
    int*            perm    = (int*)(ws + (size_t)512 * 1024);       // 256 KB
    float*          partial = (float*)(ws + (size_t)768 * 1024);     // 256 KB
    unsigned short* ell     = (unsigned short*)(ws + (size_t)1024 * 1024); // 8 MB
    float*          buf0    = (float*)(ws + (size_t)16384 * 1024);   // 32 MB
    float*          buf1    = (float*)(ws + (size_t)49152 * 1024);   // 32 MB

    // fused adjacency+ELL build; rank-space outputs
    build_ell_fused_kernel<<<NB, 512, 0, stream>>>(src, dst, ell, ocnt, dinvr,
                                                   perm);

    // bf16 w rows (513 * 80 B) + dsh (512 floats) = 43,088 B -> 2 blocks/CU
    const size_t LDSSZ = (size_t)(NN + 1) * QST * 2 + NN * 4;

    // ---- Layer 1 (X gathered via perm into rank space)
    poly_fused_kernel<<<NB * 4, 512, LDSSZ, stream>>>(X, buf0, ell, ocnt,
                                                      dinvr, perm, 1);
    gemm_bias_relu_kernel<<<BN / 128, 256, 0, stream>>>(buf0, W1, b1, buf1,
                                                        partial, 0);

    // ---- Layer 2 (all rank space, fully coalesced)
    poly_fused_kernel<<<NB * 4, 512, LDSSZ, stream>>>(buf1, buf0, ell, ocnt,
                                                      dinvr, perm, 0);
    gemm_bias_relu_kernel<<<BN / 128, 256, 0, stream>>>(buf0, W2, b2, buf1,
                                                        partial, 1);

    // ---- Readout from partials
    readout_kernel<<<NB, 128, 0, stream>>>(partial, Wr1, br1, Wr2, br2, out);
}

// Round 15
// 252.316 us; speedup vs baseline: 2.2048x; 1.0554x over previous
//
#include <hip/hip_runtime.h>
#include <hip/hip_bf16.h>

// Problem constants (match reference)
#define NB 128          // graphs
#define NN 512          // nodes per graph
#define NF 128          // feature dim
#define BN (NB*NN)      // 65536 total nodes
#define NE (BN*16)      // 1048576 edges
#define EPG 8192        // edges per graph (N*DEG_AVG)
#define WPR 16          // bitmap words per row (512 bits / 32)
#define ELLW 64         // ELL width (max padded degree)
#define QST 40          // poly w row stride in ushorts (80 B)
#define SST 72          // build-kernel ELL staging stride
#define WTS 136         // gemm Wt LDS stride in ushorts (272 B, 16-B aligned)

typedef short sh8 __attribute__((ext_vector_type(8)));
typedef float f32x4 __attribute__((ext_vector_type(4)));

static __device__ __forceinline__ unsigned short f2bf(float f) {
    unsigned u = __float_as_uint(f);
    u += 0x7fffu + ((u >> 16) & 1u);        // round-to-nearest-even
    return (unsigned short)(u >> 16);
}

// acc += bf16_low(pk)  /  acc += bf16_high(pk) via VOP3P dot2:
// D = S0.x*S1.x + S0.y*S1.y + S2 ; products exact (x1.0), +0 exact ->
// bitwise identical to shift+add, at half the instruction count.
#define DOT2LO(acc_, pk_, one_) \
    asm("v_dot2_f32_bf16 %0, %1, %2, %0" : "+v"(acc_) : "v"(pk_), "v"(one_))

// ---------------------------------------------------------------------------
// Fused adjacency + ELL build, one block per graph. LDS bitmap dedup.
// Rows ranked by degree; everything downstream lives in rank space.
// (unchanged from R13/R14)
// ---------------------------------------------------------------------------
__global__ __launch_bounds__(512) void build_ell_fused_kernel(
    const int* __restrict__ src, const int* __restrict__ dst,
    unsigned short* __restrict__ ell, int* __restrict__ ocnt,
    float* __restrict__ dinvr, int* __restrict__ perm)
{
    __shared__ unsigned bm[NN * WPR];   // 32 KB; later reused as ELL staging
    __shared__ int cs[NN];              // degree by row
    __shared__ int rdeg[NN];            // degree by rank
    __shared__ int irank[NN];           // row -> rank
    int g = blockIdx.x;
    int t = threadIdx.x;                // 0..511

    for (int i = t; i < NN * WPR; i += 512) bm[i] = 0u;
    __syncthreads();

    const int4* sg4 = (const int4*)(src + (size_t)g * EPG);
    const int4* dg4 = (const int4*)(dst + (size_t)g * EPG);
    for (int i = t; i < EPG / 4; i += 512) {
        int4 s4 = sg4[i];
        int4 d4 = dg4[i];
        int s, d;
        s = s4.x & (NN - 1); d = d4.x & (NN - 1);
        atomicOr(&bm[s * WPR + (d >> 5)], 1u << (d & 31));
        s = s4.y & (NN - 1); d = d4.y & (NN - 1);
        atomicOr(&bm[s * WPR + (d >> 5)], 1u << (d & 31));
        s = s4.z & (NN - 1); d = d4.z & (NN - 1);
        atomicOr(&bm[s * WPR + (d >> 5)], 1u << (d & 31));
        s = s4.w & (NN - 1); d = d4.w & (NN - 1);
        atomicOr(&bm[s * WPR + (d >> 5)], 1u << (d & 31));
    }
    __syncthreads();

    // extract this thread's row (row == t) into registers
    unsigned rw[WPR];
    #pragma unroll
    for (int w = 0; w < WPR; ++w) rw[w] = bm[t * WPR + w];
    int deg = 0;
    #pragma unroll
    for (int w = 0; w < WPR; ++w) deg += __popc(rw[w]);
    if (deg > ELLW) deg = ELLW;         // defensive
    cs[t] = deg;
    __syncthreads();                    // all bm reads done; cs visible

    // deterministic rank: ascending by (deg, row). LDS reads are broadcasts.
    int rk = 0;
    for (int i = 0; i < NN; ++i) {
        int di_ = cs[i];
        rk += (di_ < deg) || (di_ == deg && i < t);
    }
    rdeg[rk] = deg;
    irank[t] = rk;
    perm[(size_t)g * NN + rk] = t;
    dinvr[(size_t)g * NN + rk] = (deg > 0) ? rsqrtf((float)deg) : 0.0f;
    __syncthreads();

    if (t < NN / 8) {
        // ascending sort: oct max = last element of the oct
        int m = rdeg[t * 8 + 7];
        ocnt[(size_t)g * (NN / 8) + t] = (m + 3) & ~3;
    }

    // ELL staging (rank order, RANK-mapped entries) + coalesced writeout
    unsigned short* els = (unsigned short*)bm;
    for (int qtr = 0; qtr < 4; ++qtr) {
        if ((rk >> 7) == qtr) {
            unsigned short* er = &els[(rk & 127) * SST];
            int c = 0;
            #pragma unroll
            for (int w = 0; w < WPR; ++w) {
                unsigned bits = rw[w];
                while (bits) {
                    int j = __ffs(bits) - 1;
                    bits &= bits - 1;
                    if (c < ELLW) er[c] = (unsigned short)irank[w * 32 + j];
                    ++c;
                }
            }
            if (c > ELLW) c = ELLW;
            for (int p = c; p < ELLW; ++p) er[p] = (unsigned short)NN;
        }
        __syncthreads();
        unsigned short* outb = ell + ((size_t)g * NN + qtr * 128) * ELLW;
        for (int idx = t; idx < 1024; idx += 512) {
            int r2 = idx >> 3, sg2 = idx & 7;
            uint4 v = *(const uint4*)&els[r2 * SST + sg2 * 8];
            *(uint4*)&outb[(size_t)r2 * ELLW + sg2 * 8] = v;
        }
        __syncthreads();
    }
}

// ---------------------------------------------------------------------------
// Fused 3-hop poly conv in RANK space, one block per (graph, feature-QUARTER).
// grid = 512 blocks of 512 thr, 43 KB LDS. Gather unpack-accumulate uses
// v_dot2_f32_bf16 (1 instr per feature vs 2) — bitwise identical math.
// ---------------------------------------------------------------------------
__global__ __launch_bounds__(512, 4) void poly_fused_kernel(
    const float* __restrict__ xin,            // [BN, NF]
    float* __restrict__ accout,               // [BN, NF] rank space
    const unsigned short* __restrict__ ell,   // [BN][ELLW] rank entries
    const int* __restrict__ ocnt,             // [BN/8] padded oct counts
    const float* __restrict__ dinvr,          // [BN] rank-indexed
    const int* __restrict__ perm,             // [BN] rank -> row
    int permuteIn)
{
    extern __shared__ float lds[];
    unsigned short* w = (unsigned short*)lds;        // (NN+1) rows * QST
    float* dsh = lds + ((NN + 1) * QST * 2) / 4;     // NN floats

    int b = blockIdx.x;
    int g = b >> 2;
    int q = b & 3;                       // feature quarter
    int t = threadIdx.x;                 // 0..511
    int lane = t & 63;
    int wid  = t >> 6;                   // 0..7
    int slot = lane >> 2;                // 0..15
    int fb   = lane & 3;                 // 0..3 (8 feats each)

    unsigned one_lo = 0x00003F80u;       // bf16x2 (1.0, 0.0)
    unsigned one_hi = 0x3F800000u;       // bf16x2 (0.0, 1.0)

    if (t < NN) dsh[t] = dinvr[(size_t)g * NN + t];
    if (t < QST) w[NN * QST + t] = 0;    // zero sentinel row (bf16 0)

    int rq0 = wid * 64;                  // first rank of this wave
    int rown = rq0 + slot;               // own rank for hex x is rown + 16*x

    // input row for each hex: perm'd for layer 1, identity (coalesced) else
    int px[4];
    if (permuteIn) {
        const int* pmg = perm + (size_t)g * NN + rown;
        #pragma unroll
        for (int x = 0; x < 4; ++x) px[x] = pmg[16 * x];
    } else {
        #pragma unroll
        for (int x = 0; x < 4; ++x) px[x] = rown + 16 * x;
    }

    const float* xg = xin + (size_t)g * NN * NF + q * 32 + fb * 8;

    float acc[4][8];
    #pragma unroll
    for (int x = 0; x < 4; ++x) {
        int row = px[x];
        float4 a0 = *(const float4*)&xg[(size_t)row * NF];
        float4 a1 = *(const float4*)&xg[(size_t)row * NF + 4];
        acc[x][0] = a0.x; acc[x][1] = a0.y; acc[x][2] = a0.z; acc[x][3] = a0.w;
        acc[x][4] = a1.x; acc[x][5] = a1.y; acc[x][6] = a1.z; acc[x][7] = a1.w;
    }

    // per-hex counts = max of the hex's two oct counts (wave-uniform)
    const int* oc = ocnt + (((size_t)g * NN + rq0) >> 3);
    int co[4];
    #pragma unroll
    for (int x = 0; x < 4; ++x)
        co[x] = __builtin_amdgcn_readfirstlane(max(oc[2 * x], oc[2 * x + 1]));

    __syncthreads();                     // dsh + sentinel ready

    #pragma unroll
    for (int x = 0; x < 4; ++x) {
        int rr = rown + 16 * x;          // rank position
        float di = dsh[rr];
        unsigned pk[4];
        #pragma unroll
        for (int k = 0; k < 4; ++k) {
            unsigned lo = (unsigned)f2bf(di * acc[x][2 * k]);
            unsigned hi = (unsigned)f2bf(di * acc[x][2 * k + 1]);
            pk[k] = lo | (hi << 16);
        }
        *(uint4*)&w[rr * QST + fb * 8] = make_uint4(pk[0], pk[1], pk[2], pk[3]);
    }
    __syncthreads();                     // w init ready

    const unsigned short* elbase = ell + ((size_t)g * NN + rown) * ELLW;

    for (int hop = 0; hop < 3; ++hop) {
        float stage[4][8];
        ushort4 nq = *(const ushort4*)elbase;   // hex 0, batch 0
        #pragma unroll
        for (int x = 0; x < 4; ++x) {
            const unsigned short* el = elbase + (size_t)(16 * x) * ELLW;
            int cnt = co[x];
            ushort4 cur = nq;
            if (x < 3)                   // prefetch next hex's first batch
                nq = *(const ushort4*)(elbase + (size_t)(16 * (x + 1)) * ELLW);
            float s[8];
            #pragma unroll
            for (int k = 0; k < 8; ++k) s[k] = 0.0f;
            for (int p = 0; p < cnt; p += 4) {
                ushort4 nxt = cur;
                if (p + 4 < cnt) nxt = *(const ushort4*)(el + p + 4);
                uint4 v0 = *(const uint4*)&w[(int)cur.x * QST + fb * 8];
                uint4 v1 = *(const uint4*)&w[(int)cur.y * QST + fb * 8];
                uint4 v2 = *(const uint4*)&w[(int)cur.z * QST + fb * 8];
                uint4 v3 = *(const uint4*)&w[(int)cur.w * QST + fb * 8];
                unsigned d[4][4] = {{v0.x, v0.y, v0.z, v0.w},
                                    {v1.x, v1.y, v1.z, v1.w},
                                    {v2.x, v2.y, v2.z, v2.w},
                                    {v3.x, v3.y, v3.z, v3.w}};
                #pragma unroll
                for (int n = 0; n < 4; ++n) {
                    #pragma unroll
                    for (int k = 0; k < 4; ++k) {
                        DOT2LO(s[2 * k],     d[n][k], one_lo);
                        DOT2LO(s[2 * k + 1], d[n][k], one_hi);
                    }
                }
                cur = nxt;
            }
            #pragma unroll
            for (int k = 0; k < 8; ++k) stage[x][k] = s[k];
        }
        __syncthreads();                 // all reads of old w done
        #pragma unroll
        for (int x = 0; x < 4; ++x) {
            int rr = rown + 16 * x;
            float di = dsh[rr];
            unsigned pk[4];
            #pragma unroll
            for (int k = 0; k < 4; ++k) {
                float zlo = di * stage[x][2 * k];
                float zhi = di * stage[x][2 * k + 1];
                acc[x][2 * k]     += zlo;
                acc[x][2 * k + 1] += zhi;
                unsigned lo = (unsigned)f2bf(di * zlo);
                unsigned hi = (unsigned)f2bf(di * zhi);
                pk[k] = lo | (hi << 16);
            }
            *(uint4*)&w[rr * QST + fb * 8] = make_uint4(pk[0], pk[1], pk[2], pk[3]);
        }
        __syncthreads();                 // new w visible
    }

    // coalesced write at rank positions
    float* og = accout + (size_t)g * NN * NF + q * 32 + fb * 8;
    #pragma unroll
    for (int x = 0; x < 4; ++x) {
        int rr = rown + 16 * x;
        *(float4*)&og[(size_t)rr * NF] =
            make_float4(acc[x][0], acc[x][1], acc[x][2], acc[x][3]);
        *(float4*)&og[(size_t)rr * NF + 4] =
            make_float4(acc[x][4], acc[x][5], acc[x][6], acc[x][7]);
    }
}

// ---------------------------------------------------------------------------
// MFMA bf16 GEMM: Y[65536,128] = relu(bf16(X) @ bf16(W) + b), optional fused
// deterministic mean-pool partials. (unchanged from R13)
// ---------------------------------------------------------------------------
__global__ __launch_bounds__(256, 2) void gemm_bias_relu_kernel(
    const float* __restrict__ X, const float* __restrict__ W,
    const float* __restrict__ b, float* __restrict__ Y,
    float* __restrict__ partial, int fuse)
{
    __shared__ __align__(16) unsigned short Wt[NF * WTS];  // [n][k] bf16
    __shared__ float part[4 * NF];

    int t = threadIdx.x;

    // stage Wt = W^T in bf16
    for (int i = t; i < NF * NF / 4; i += 256) {
        int k = i >> 5;                 // W row
        int n4 = (i & 31) * 4;          // W col group
        float4 wv = ((const float4*)W)[i];
        Wt[(n4 + 0) * WTS + k] = f2bf(wv.x);
        Wt[(n4 + 1) * WTS + k] = f2bf(wv.y);
        Wt[(n4 + 2) * WTS + k] = f2bf(wv.z);
        Wt[(n4 + 3) * WTS + k] = f2bf(wv.w);
    }
    __syncthreads();

    int lane = t & 63;
    int wid  = t >> 6;                  // 0..3
    int quad = lane >> 4;               // 0..3
    int l16  = lane & 15;
    int rowA0 = blockIdx.x * 128 + wid * 32;

    // A fragments: af[m][kk], m in {0,1} (row halves), kk = K-step
    union { unsigned short u[8]; sh8 v; } af[2][4];
    #pragma unroll
    for (int m = 0; m < 2; ++m) {
        int r = rowA0 + m * 16 + l16;
        const float* xr = X + (size_t)r * NF + quad * 8;
        #pragma unroll
        for (int kk = 0; kk < 4; ++kk) {
            float4 x0 = *(const float4*)(xr + kk * 32);
            float4 x1 = *(const float4*)(xr + kk * 32 + 4);
            af[m][kk].u[0] = f2bf(x0.x); af[m][kk].u[1] = f2bf(x0.y);
            af[m][kk].u[2] = f2bf(x0.z); af[m][kk].u[3] = f2bf(x0.w);
            af[m][kk].u[4] = f2bf(x1.x); af[m][kk].u[5] = f2bf(x1.y);
            af[m][kk].u[6] = f2bf(x1.z); af[m][kk].u[7] = f2bf(x1.w);
        }
    }

    f32x4 acc[2][8];
    #pragma unroll
    for (int m = 0; m < 2; ++m)
        #pragma unroll
        for (int c = 0; c < 8; ++c) acc[m][c] = (f32x4){0.f, 0.f, 0.f, 0.f};

    #pragma unroll
    for (int c = 0; c < 8; ++c) {
        const unsigned short* wb = &Wt[(c * 16 + l16) * WTS + quad * 8];
        #pragma unroll
        for (int kk = 0; kk < 4; ++kk) {
            union { uint4 q; sh8 v; } bf_;
            bf_.q = *(const uint4*)(wb + kk * 32);
            acc[0][c] = __builtin_amdgcn_mfma_f32_16x16x32_bf16(
                af[0][kk].v, bf_.v, acc[0][c], 0, 0, 0);
            acc[1][c] = __builtin_amdgcn_mfma_f32_16x16x32_bf16(
                af[1][kk].v, bf_.v, acc[1][c], 0, 0, 0);
        }
    }

    float psum[8];
    #pragma unroll
    for (int c = 0; c < 8; ++c) psum[c] = 0.0f;

    #pragma unroll
    for (int c = 0; c < 8; ++c) {
        int col = c * 16 + l16;
        float bias = b[col];
        #pragma unroll
        for (int m = 0; m < 2; ++m) {
            #pragma unroll
            for (int reg = 0; reg < 4; ++reg) {
                int r = rowA0 + m * 16 + quad * 4 + reg;
                float v = fmaxf(acc[m][c][reg] + bias, 0.0f);
                Y[(size_t)r * NF + col] = v;
                psum[c] += v;
            }
        }
    }

    if (fuse) {
        // deterministic cross-quad reduction, then cross-wave LDS tree
        #pragma unroll
        for (int c = 0; c < 8; ++c) {
            float v = psum[c];
            v += __shfl_xor(v, 16);
            v += __shfl_xor(v, 32);
            if (lane < 16) part[wid * NF + c * 16 + lane] = v;
        }
        __syncthreads();
        if (t < NF) {
            float s = part[t] + part[NF + t] + part[2 * NF + t]
                    + part[3 * NF + t];
            partial[(size_t)blockIdx.x * NF + t] = s;
        }
    }
}

// ---------------------------------------------------------------------------
// Readout: per graph, mean-pool from gemm2 partials (4 blocks/graph) + MLP.
// ---------------------------------------------------------------------------
__global__ __launch_bounds__(128) void readout_kernel(
    const float* __restrict__ partial,   // [BN/128][NF]
    const float* __restrict__ Wr1, const float* __restrict__ br1,
    const float* __restrict__ Wr2, const float* __restrict__ br2,
    float* __restrict__ out)
{
    __shared__ float hsh[NF];
    __shared__ float r1[64];

    int g = blockIdx.x;
    int t = threadIdx.x;

    const float* pg = partial + (size_t)g * 4 * NF;
    float s = 0.0f;
    #pragma unroll
    for (int j = 0; j < 4; ++j) s += pg[j * NF + t];
    hsh[t] = s * (1.0f / (float)NN);
    __syncthreads();

    if (t < 64) {
        float a = br1[t];
        #pragma unroll 8
        for (int k = 0; k < NF; ++k) a += hsh[k] * Wr1[k * 64 + t];
        r1[t] = fmaxf(a, 0.0f);
    }
    __syncthreads();

    if (t < 64) {
        float v = r1[t] * Wr2[t];
        #pragma unroll
        for (int off = 32; off; off >>= 1) v += __shfl_down(v, off);
        if (t == 0) out[g] = v + br2[0];
    }
}

// ---------------------------------------------------------------------------
extern "C" void kernel_launch(void* const* d_in, const int* in_sizes, int n_in,
                              void* d_out, int out_size, void* d_ws, size_t ws_size,
                              hipStream_t stream)
{
    const float* X    = (const float*)d_in[0];
    // d_in[1] = batch (unused; nodes already grouped per graph)
    const int*   ei   = (const int*)d_in[2];
    const float* W1   = (const float*)d_in[3];
    const float* b1   = (const float*)d_in[4];
    const float* W2   = (const float*)d_in[5];
    const float* b2   = (const float*)d_in[6];
    const float* Wr1  = (const float*)d_in[7];
    const float* br1  = (const float*)d_in[8];
    const float* Wr2  = (const float*)d_in[9];
    const float* br2  = (const float*)d_in[10];
    float* out = (float*)d_out;

    const int* src = ei;
    const int* dst = ei + NE;

    // workspace layout
    char* ws = (char*)d_ws;
    float*          dinvr   = (float*)(ws);                          // 256 KB
    int*            ocnt    = (int*)(ws + (size_t)256 * 1024);       // 32 KB
    int*            perm    = (int*)(ws + (size_t)512 * 1024);       // 256 KB
    float*          partial = (float*)(ws + (size_t)768 * 1024);     // 256 KB
    unsigned short* ell     = (unsigned short*)(ws + (size_t)1024 * 1024); // 8 MB
    float*          buf0    = (float*)(ws + (size_t)16384 * 1024);   // 32 MB
    float*          buf1    = (float*)(ws + (size_t)49152 * 1024);   // 32 MB

    // fused adjacency+ELL build; rank-space outputs
    build_ell_fused_kernel<<<NB, 512, 0, stream>>>(src, dst, ell, ocnt, dinvr,
                                                   perm);

    // bf16 w rows (513 * 80 B) + dsh (512 floats) = 43,088 B
    const size_t LDSSZ = (size_t)(NN + 1) * QST * 2 + NN * 4;

    // ---- Layer 1 (X gathered via perm into rank space)
    poly_fused_kernel<<<NB * 4, 512, LDSSZ, stream>>>(X, buf0, ell, ocnt,
                                                      dinvr, perm, 1);
    gemm_bias_relu_kernel<<<BN / 128, 256, 0, stream>>>(buf0, W1, b1, buf1,
                                                        partial, 0);

    // ---- Layer 2 (all rank space, fully coalesced)
    poly_fused_kernel<<<NB * 4, 512, LDSSZ, stream>>>(buf1, buf0, ell, ocnt,
                                                      dinvr, perm, 0);
    gemm_bias_relu_kernel<<<BN / 128, 256, 0, stream>>>(buf0, W2, b2, buf1,
                                                        partial, 1);

    // ---- Readout from partials
    readout_kernel<<<NB, 128, 0, stream>>>(partial, Wr1, br1, Wr2, br2, out);
}